// Round 4
// baseline (379.153 us; speedup 1.0000x reference)
//
#include <hip/hip_runtime.h>
#include <hip/hip_bf16.h>

#define Bq 8
#define Nq 1024
#define Dq 768
#define Hq 12
#define Zq 64
#define HIDq 3072
#define BN (Bq*Nq)            // 8192
#define QKP 1536              // pitch of fused QK / AV12 buffers

typedef unsigned short u16;
typedef short s16x8 __attribute__((ext_vector_type(8)));
typedef float f32x4 __attribute__((ext_vector_type(4)));
typedef unsigned short u16x4 __attribute__((ext_vector_type(4)));

#define MFMA16 __builtin_amdgcn_mfma_f32_16x16x32_bf16
#define GLOAD16(g, l) __builtin_amdgcn_global_load_lds( \
    (const __attribute__((address_space(1))) void*)(const void*)(g), \
    (__attribute__((address_space(3))) void*)(l), 16, 0, 0)

__device__ __forceinline__ u16 f2bf(float f) {
  unsigned u = __float_as_uint(f);
  return (u16)((u + 0x7FFFu + ((u >> 16) & 1u)) >> 16);
}

// paired f32->bf16 (v_cvt_pk_bf16_f32; RNE, matches f2bf)
__device__ __forceinline__ unsigned pk2bf(float a, float b) {
  union { __hip_bfloat162 h; unsigned u; } cv;
  cv.h.x = __float2bfloat16(a);
  cv.h.y = __float2bfloat16(b);
  return cv.u;
}

// XCD-aware swizzle: all gx tiles of a row-panel (and gy/8 consecutive panels)
// land on one XCD (dispatch round-robins linear id % 8). Requires gy % 8 == 0.
__device__ __forceinline__ void xcd_swizzle(int gx, int gy, int& bx, int& by) {
  int l = blockIdx.y * gx + blockIdx.x;
  int c = l & 7, j = l >> 3;
  by = c * (gy >> 3) + j / gx;
  bx = j % gx;
}

// ---------------------------------------------------------------------------
// f32 -> bf16 convert, TWO tensors in one dispatch (x then Wm)
// blocks 0..6143 -> x (BN*Dq), 6144..8447 -> Wm (HIDq*Dq)
// ---------------------------------------------------------------------------
__global__ __launch_bounds__(256) void cvt2(const float* __restrict__ x, u16* __restrict__ xb,
                                            const float* __restrict__ Wm, u16* __restrict__ Wmb) {
  int bid = blockIdx.x;
  const float* in; u16* out; int i;
  if (bid < 6144) { in = x;  out = xb;  i = bid * 1024 + threadIdx.x * 4; }
  else            { in = Wm; out = Wmb; i = (bid - 6144) * 1024 + threadIdx.x * 4; }
  float4 v = *(const float4*)&in[i];
  u16x4 o; o[0] = f2bf(v.x); o[1] = f2bf(v.y); o[2] = f2bf(v.z); o[3] = f2bf(v.w);
  *(u16x4*)&out[i] = o;
}

// ---------------------------------------------------------------------------
// Wq/Wk f32 [768][768] -> bf16 [row-major into Wqkb slab] AND transposed into
// WqkT [768][1536]. grid (12, 12, 2): z=0 -> Wq, z=1 -> Wk.
// ---------------------------------------------------------------------------
__global__ __launch_bounds__(256) void cvt_tr2(const float* __restrict__ Wq,
                                               const float* __restrict__ Wk,
                                               u16* __restrict__ Wqkb,
                                               u16* __restrict__ WqkT) {
  __shared__ u16 T[64][72];
  const int t = threadIdx.x;
  const int z = blockIdx.z;
  const float* in = z ? Wk : Wq;
  u16* out = Wqkb + (size_t)z * Dq * Dq;
  u16* outT = WqkT + z * Dq;
  const int r0 = blockIdx.y * 64, c0 = blockIdx.x * 64;
  const int r = t >> 3, c8 = (t & 7) * 8;
#pragma unroll
  for (int p = 0; p < 2; p++) {
    const float* ip = &in[(size_t)(r0 + r + p * 32) * Dq + c0 + c8];
    float4 v0 = *(const float4*)ip, v1 = *(const float4*)(ip + 4);
    u16 tmp[8] = {f2bf(v0.x), f2bf(v0.y), f2bf(v0.z), f2bf(v0.w),
                  f2bf(v1.x), f2bf(v1.y), f2bf(v1.z), f2bf(v1.w)};
    *(uint4*)&out[(size_t)(r0 + r + p * 32) * Dq + c0 + c8] = *(uint4*)tmp;
    *(uint4*)&T[r + p * 32][c8] = *(uint4*)tmp;
  }
  __syncthreads();
#pragma unroll
  for (int p = 0; p < 2; p++) {
    int oc = r + p * 32;
    u16 tmp[8];
#pragma unroll
    for (int j = 0; j < 8; j++) tmp[j] = T[c8 + j][oc];
    *(uint4*)&outT[(size_t)(c0 + oc) * QKP + r0 + c8] = *(uint4*)tmp;
  }
}

// ---------------------------------------------------------------------------
// Batched 64x64-tiled bf16 transpose (used for WmT only).
// ---------------------------------------------------------------------------
__global__ __launch_bounds__(256) void transpose_bf16(
    const u16* __restrict__ in, u16* __restrict__ out,
    int in_pitch, int out_pitch, int inner_n,
    long in_bs_o, long in_bs_i, long out_bs_o, long out_bs_i) {
  __shared__ u16 T[64][72];
  const int t = threadIdx.x;
  const int bz = blockIdx.z;
  const long iboff = (long)(bz / inner_n) * in_bs_o + (long)(bz % inner_n) * in_bs_i;
  const long oboff = (long)(bz / inner_n) * out_bs_o + (long)(bz % inner_n) * out_bs_i;
  const u16* ip = in + iboff + (long)(blockIdx.y * 64) * in_pitch + blockIdx.x * 64;
  u16* op = out + oboff + (long)(blockIdx.x * 64) * out_pitch + blockIdx.y * 64;
  const int r = t >> 3, c8 = (t & 7) * 8;
#pragma unroll
  for (int p = 0; p < 2; p++)
    *(uint4*)&T[r + p * 32][c8] = *(const uint4*)(ip + (size_t)(r + p * 32) * in_pitch + c8);
  __syncthreads();
#pragma unroll
  for (int p = 0; p < 2; p++) {
    int oc = r + p * 32;
    u16 tmp[8];
#pragma unroll
    for (int j = 0; j < 8; j++) tmp[j] = T[c8 + j][oc];
    *(uint4*)(op + (size_t)oc * out_pitch + c8) = *(uint4*)tmp;
  }
}

// ---------------------------------------------------------------------------
// Per-head transposes of Q and K in ONE dispatch. grid (1, 16, 192):
// z 0..95 -> Q panel (cols 0:768 of QKb), z 96..191 -> K panel (cols 768:1536).
// ---------------------------------------------------------------------------
__global__ __launch_bounds__(256) void head_tr(const u16* __restrict__ QKb,
                                               u16* __restrict__ QbT,
                                               u16* __restrict__ KbT) {
  __shared__ u16 T[64][72];
  const int t = threadIdx.x;
  const int z = blockIdx.z;
  const int half = (z >= 96) ? 1 : 0;
  const int bhh = z - 96 * half;
  const u16* ip = QKb + (size_t)(bhh / Hq) * Nq * QKP + (bhh % Hq) * 64 + half * Dq
                + (size_t)(blockIdx.y * 64) * QKP;
  u16* op = (half ? KbT : QbT) + (size_t)bhh * 64 * Nq + blockIdx.y * 64;
  const int r = t >> 3, c8 = (t & 7) * 8;
#pragma unroll
  for (int p = 0; p < 2; p++)
    *(uint4*)&T[r + p * 32][c8] = *(const uint4*)(ip + (size_t)(r + p * 32) * QKP + c8);
  __syncthreads();
#pragma unroll
  for (int p = 0; p < 2; p++) {
    int oc = r + p * 32;
    u16 tmp[8];
#pragma unroll
    for (int j = 0; j < 8; j++) tmp[j] = T[c8 + j][oc];
    *(uint4*)(op + (size_t)oc * Nq + c8) = *(uint4*)tmp;
  }
}

// ---------------------------------------------------------------------------
// bf16 MFMA GEMM: C[M,N] = A[M,K] * B[N,K]^T, bf16 out. 128x128 tile, BK=32,
// double-buffered single-barrier pipeline. XCD-swizzled. LDS 32 KB.
// ---------------------------------------------------------------------------
template<bool RELU>
__global__ __launch_bounds__(256) void gemm_bf16(
    const u16* __restrict__ A, const u16* __restrict__ B, u16* __restrict__ C,
    int M, int N, int K) {
  __shared__ u16 As[2][128 * 32];
  __shared__ u16 Bs[2][128 * 32];
  int bx, by;
  xcd_swizzle(gridDim.x, gridDim.y, bx, by);
  const int t = threadIdx.x, l = t & 63, w = t >> 6;
  const int lq = l & 15, quad = l >> 4;
  const int bm = by * 128, bn = bx * 128;
  const int wm = (w & 1) * 64, wn = (w >> 1) * 64;
  f32x4 acc[4][4];
#pragma unroll
  for (int i = 0; i < 4; i++)
#pragma unroll
    for (int j = 0; j < 4; j++) acc[i][j] = (f32x4){0.f, 0.f, 0.f, 0.f};

  auto stage = [&](int k0, int bufi) {
#pragma unroll
    for (int p = 0; p < 2; p++) {
      int idx = p * 256 + t;
      GLOAD16(A + (size_t)(bm + (idx >> 2)) * K + k0 + (idx & 3) * 8, &As[bufi][idx * 8]);
      GLOAD16(B + (size_t)(bn + (idx >> 2)) * K + k0 + (idx & 3) * 8, &Bs[bufi][idx * 8]);
    }
  };
  stage(0, 0);
  const int nIter = K >> 5;
  for (int it = 0; it < nIter; it++) {
    __syncthreads();
    if (it + 1 < nIter) stage((it + 1) * 32, (it + 1) & 1);
    const int bi = it & 1;
    s16x8 af[4], bf[4];
#pragma unroll
    for (int mt = 0; mt < 4; mt++)
      af[mt] = *(const s16x8*)&As[bi][(wm + mt * 16 + lq) * 32 + quad * 8];
#pragma unroll
    for (int nt = 0; nt < 4; nt++)
      bf[nt] = *(const s16x8*)&Bs[bi][(wn + nt * 16 + lq) * 32 + quad * 8];
#pragma unroll
    for (int mt = 0; mt < 4; mt++)
#pragma unroll
      for (int nt = 0; nt < 4; nt++)
        acc[mt][nt] = MFMA16(af[mt], bf[nt], acc[mt][nt], 0, 0, 0);
  }
#pragma unroll
  for (int mt = 0; mt < 4; mt++)
#pragma unroll
    for (int nt = 0; nt < 4; nt++) {
      int row = bm + wm + mt * 16 + quad * 4;
      int col = bn + wn + nt * 16 + lq;
#pragma unroll
      for (int r = 0; r < 4; r++) {
        float v = acc[mt][nt][r];
        if (RELU) v = fmaxf(v, 0.f);
        C[(size_t)(row + r) * N + col] = f2bf(v);
      }
    }
}

// ---------------------------------------------------------------------------
// Fused output GEMM (no atomics): 128x64 tile of out[8192][768], accumulating
//   out = AV12[8192][1536] @ WqkT^T + hid[8192][3072] @ WmT^T
// BK=64 (72 tiles), double-buffered single-barrier pipeline. LDS 48 KB.
// ---------------------------------------------------------------------------
__global__ __launch_bounds__(256) void gemm_out2(
    const u16* __restrict__ AV12, const u16* __restrict__ hid,
    const u16* __restrict__ WqkT, const u16* __restrict__ WmT,
    float* __restrict__ out) {
  __shared__ u16 As[2][128 * 64];   // 32 KB
  __shared__ u16 Bs[2][64 * 64];    // 16 KB
  int bx, by;
  xcd_swizzle(gridDim.x, gridDim.y, bx, by);
  const int t = threadIdx.x, l = t & 63, w = t >> 6;
  const int lq = l & 15, quad = l >> 4;
  const int bm = by * 128, bn = bx * 64;
  const int wm = w * 32;
  f32x4 acc[2][4];
#pragma unroll
  for (int i = 0; i < 2; i++)
#pragma unroll
    for (int j = 0; j < 4; j++) acc[i][j] = (f32x4){0.f, 0.f, 0.f, 0.f};

  auto stage = [&](int tl, int bufi) {
    const u16* A; const u16* B; int pitch, k0;
    if (tl < 24) { A = AV12; B = WqkT; pitch = QKP;  k0 = tl * 64; }
    else         { A = hid;  B = WmT;  pitch = HIDq; k0 = (tl - 24) * 64; }
#pragma unroll
    for (int p = 0; p < 4; p++) {
      int idx = p * 256 + t, ks = idx >> 9, rem = idx & 511;
      GLOAD16(A + (size_t)(bm + (rem >> 2)) * pitch + k0 + ks * 32 + (rem & 3) * 8,
              &As[bufi][idx * 8]);
    }
#pragma unroll
    for (int p = 0; p < 2; p++) {
      int idx = p * 256 + t, ks = idx >> 8, rem = idx & 255;
      GLOAD16(B + (size_t)(bn + (rem >> 2)) * pitch + k0 + ks * 32 + (rem & 3) * 8,
              &Bs[bufi][idx * 8]);
    }
  };
  stage(0, 0);
  for (int tl = 0; tl < 72; tl++) {
    __syncthreads();
    if (tl + 1 < 72) stage(tl + 1, (tl + 1) & 1);
    const int bi = tl & 1;
#pragma unroll
    for (int ks = 0; ks < 2; ks++) {
      s16x8 af[2], bf[4];
#pragma unroll
      for (int mt = 0; mt < 2; mt++)
        af[mt] = *(const s16x8*)&As[bi][ks * 4096 + (wm + mt * 16 + lq) * 32 + quad * 8];
#pragma unroll
      for (int nt = 0; nt < 4; nt++)
        bf[nt] = *(const s16x8*)&Bs[bi][ks * 2048 + (nt * 16 + lq) * 32 + quad * 8];
#pragma unroll
      for (int mt = 0; mt < 2; mt++)
#pragma unroll
        for (int nt = 0; nt < 4; nt++)
          acc[mt][nt] = MFMA16(af[mt], bf[nt], acc[mt][nt], 0, 0, 0);
    }
  }
#pragma unroll
  for (int mt = 0; mt < 2; mt++)
#pragma unroll
    for (int nt = 0; nt < 4; nt++) {
      int row = bm + wm + mt * 16 + quad * 4;
      int col = bn + nt * 16 + lq;
#pragma unroll
      for (int r = 0; r < 4; r++)
        out[(size_t)(row + r) * Dq + col] = acc[mt][nt][r];
    }
}

// ---------------------------------------------------------------------------
// Attention pass 1, register-softmax version. Per (b,h,64-q) block.
// Wave w owns q-rows w*16..w*16+15. Per kt iteration (ONE barrier):
//   S-MFMAs: A = K k-subtiles (LDS), B = wave's private Q frag ->
//     lane(lq,quad) holds S[k = s*16+quad*4+r][q = w*16+lq] in sc[s][r]
//   exp -> pw[s][h] bf16 pairs; lsum per-lane (q = w*16+lq)
//   quad-permute via 16 shfl + 8 select -> PV A-frags in registers (NO Ps LDS!)
//     af[m] word p = pw[2m + (quad>>1)][p&1] from lane lq + 16*((quad&1)*2 + (p>>1))
//     (k = m*32 + quad*8 + 2p = (2m+(quad>>1))*16 + ((quad&1)*2+(p>>1))*4 + 2(p&1))
//   PV-MFMAs: B = Kt z-rows (LDS)
// K/Kt double-buffered, staged right after the barrier. LDS 40960 B -> 4 blk/CU.
// ---------------------------------------------------------------------------
__global__ __launch_bounds__(256) void attn_pass1(
    const u16* __restrict__ QKb, const u16* __restrict__ KbT,
    const float* __restrict__ betas, u16* __restrict__ AV12,
    float* __restrict__ lg) {
  __shared__ u16 Qs[2][64][32];       // 8 KB; li overlays after frag hoist
  __shared__ u16 Ks[2][2][64][32];    // 16 KB dbuf [buf][zs][k-row][32]
  __shared__ u16 Kts[2][2][64][32];   // 16 KB dbuf [buf][k-half][z-row][32]

  const int t = threadIdx.x, l = t & 63, w = t >> 6;
  const int lq = l & 15, quad = l >> 4;
  const int c = blockIdx.x & 7, j = blockIdx.x >> 3;
  const int bh = c * 12 + j / 16, qt = j % 16;
  const int b = bh / Hq, h = bh % Hq;
  const int q0 = qt * 64;
  const float beta = betas[h];
  const u16* Qh = QKb + (size_t)(b * Nq) * QKP + h * 64;
  const u16* Kh = Qh + Dq;
  const u16* KTh = KbT + (size_t)bh * 64 * Nq;

  auto stageK = [&](int kt, int bufi) {
#pragma unroll
    for (int p = 0; p < 2; p++) {
      int idx = p * 256 + t;
      GLOAD16(Kh + (size_t)(kt * 64 + ((idx >> 2) & 63)) * QKP + (idx >> 8) * 32 + (idx & 3) * 8,
              &Ks[bufi][0][0][0] + idx * 8);
      GLOAD16(KTh + (size_t)((idx >> 2) & 63) * Nq + kt * 64 + (idx >> 8) * 32 + (idx & 3) * 8,
              &Kts[bufi][0][0][0] + idx * 8);
    }
  };
  // prologue: Q + tile 0
#pragma unroll
  for (int p = 0; p < 2; p++) {
    int idx = p * 256 + t;
    GLOAD16(Qh + (size_t)(q0 + ((idx >> 2) & 63)) * QKP + (idx >> 8) * 32 + (idx & 3) * 8,
            &Qs[0][0][0] + idx * 8);
  }
  stageK(0, 0);
  __syncthreads();
  s16x8 bqf[2];
#pragma unroll
  for (int zs = 0; zs < 2; zs++)
    bqf[zs] = *(const s16x8*)&Qs[zs][w * 16 + lq][quad * 8];

  float lsum = 0.f;
  f32x4 ao[4];
#pragma unroll
  for (int nt = 0; nt < 4; nt++) ao[nt] = (f32x4){0.f, 0.f, 0.f, 0.f};

  const int ybase = lq + ((quad & 1) << 5);
  for (int kt = 0; kt < 16; kt++) {
    if (kt) __syncthreads();             // stage(kt) landed; buf[bi^1] reads done
    if (kt + 1 < 16) stageK(kt + 1, (kt + 1) & 1);
    const int bi = kt & 1;
    f32x4 sc[4];
#pragma unroll
    for (int s = 0; s < 4; s++) sc[s] = (f32x4){0.f, 0.f, 0.f, 0.f};
#pragma unroll
    for (int zs = 0; zs < 2; zs++)
#pragma unroll
      for (int s = 0; s < 4; s++) {
        s16x8 a = *(const s16x8*)&Ks[bi][zs][s * 16 + lq][quad * 8];
        sc[s] = MFMA16(a, bqf[zs], sc[s], 0, 0, 0);
      }
    unsigned pw[4][2];
#pragma unroll
    for (int s = 0; s < 4; s++) {
      float e0 = __expf(sc[s][0] * beta), e1 = __expf(sc[s][1] * beta);
      float e2 = __expf(sc[s][2] * beta), e3 = __expf(sc[s][3] * beta);
      lsum += (e0 + e1) + (e2 + e3);
      pw[s][0] = pk2bf(e0, e1);
      pw[s][1] = pk2bf(e2, e3);
    }
#pragma unroll
    for (int m = 0; m < 2; m++) {
      union { unsigned u[4]; s16x8 v; } af;
#pragma unroll
      for (int p = 0; p < 4; p++) {
        int y = ybase + ((p >> 1) << 4);
        unsigned lo = (unsigned)__shfl((int)pw[2 * m][p & 1], y, 64);
        unsigned hi = (unsigned)__shfl((int)pw[2 * m + 1][p & 1], y, 64);
        af.u[p] = (quad < 2) ? lo : hi;
      }
#pragma unroll
      for (int nt = 0; nt < 4; nt++) {
        s16x8 bk = *(const s16x8*)&Kts[bi][m][nt * 16 + lq][quad * 8];
        ao[nt] = MFMA16(af.v, bk, ao[nt], 0, 0, 0);
      }
    }
  }
  // l reduce: lane's lsum is partial (its quad's k share) for q = w*16+lq
  float v = lsum;
  v += __shfl_xor(v, 16, 64);
  v += __shfl_xor(v, 32, 64);
  float* lip = (float*)&Qs[0][0][0];     // Qs dead since hoist; wave-local slices
  if (l < 16) {
    lg[(size_t)bh * Nq + q0 + w * 16 + lq] = v;
    lip[w * 16 + lq] = 1.0f / v;
  }
  float lr[4];
#pragma unroll
  for (int r = 0; r < 4; r++) lr[r] = lip[w * 16 + quad * 4 + r];
  u16* Oh = AV12 + (size_t)(b * Nq + q0) * QKP + h * 64;
#pragma unroll
  for (int nt = 0; nt < 4; nt++)
#pragma unroll
    for (int r = 0; r < 4; r++)
      Oh[(size_t)(w * 16 + quad * 4 + r) * QKP + nt * 16 + lq] = f2bf(ao[nt][r] * lr[r]);
}

// ---------------------------------------------------------------------------
// Attention pass 2, register-softmax version. Per (b,h,64-k) block.
// Wave w owns k-rows w*16..w*16+15 (B = wave's private K frag, hoisted).
// Streams q-tiles; sc[s][r] = S[q = s*16+quad*4+r][k = w*16+lq]; normalized
// P packed in-register, same quad-permute as pass1 (q plays pass1's k role),
// PV B = Qt z-rows. li table double-buffered in LDS (overlaid on dead KsS).
// LDS 40960 B -> 4 blocks/CU. ONE barrier per iteration.
// ---------------------------------------------------------------------------
__global__ __launch_bounds__(256) void attn_pass2(
    const u16* __restrict__ QKb, const u16* __restrict__ QbT,
    const float* __restrict__ betas, u16* __restrict__ AV12,
    const float* __restrict__ lg) {
  __shared__ u16 Qs[2][2][64][32];     // 16 KB dbuf [buf][zs][q-row][32]
  __shared__ u16 Qts[2][2][64][32];    // 16 KB dbuf [buf][q-half][z-row][32]
  __shared__ u16 KsS[2][64][32];       // 8 KB; li_s[2][64] overlays after hoist

  const int t = threadIdx.x, l = t & 63, w = t >> 6;
  const int lq = l & 15, quad = l >> 4;
  const int c = blockIdx.x & 7, j = blockIdx.x >> 3;
  const int bh = c * 12 + j / 16, kt = j % 16;
  const int b = bh / Hq, h = bh % Hq;
  const int k0 = kt * 64;
  const float beta = betas[h];
  const u16* Qh = QKb + (size_t)(b * Nq) * QKP + h * 64;
  const u16* Kh = Qh + Dq;
  const u16* QTh = QbT + (size_t)bh * 64 * Nq;
  float* lis = (float*)&KsS[0][0][0];  // [2][64] after hoist

  auto stageQ = [&](int qt2, int bufi) {
#pragma unroll
    for (int p = 0; p < 2; p++) {
      int idx = p * 256 + t;
      GLOAD16(Qh + (size_t)(qt2 * 64 + ((idx >> 2) & 63)) * QKP + (idx >> 8) * 32 + (idx & 3) * 8,
              &Qs[bufi][0][0][0] + idx * 8);
      GLOAD16(QTh + (size_t)((idx >> 2) & 63) * Nq + qt2 * 64 + (idx >> 8) * 32 + (idx & 3) * 8,
              &Qts[bufi][0][0][0] + idx * 8);
    }
  };
  // prologue: K rows + q-tile 0
#pragma unroll
  for (int p = 0; p < 2; p++) {
    int idx = p * 256 + t;
    GLOAD16(Kh + (size_t)(k0 + ((idx >> 2) & 63)) * QKP + (idx >> 8) * 32 + (idx & 3) * 8,
            &KsS[0][0][0] + idx * 8);
  }
  stageQ(0, 0);
  __syncthreads();
  s16x8 bkw[2];
#pragma unroll
  for (int zs = 0; zs < 2; zs++)
    bkw[zs] = *(const s16x8*)&KsS[zs][w * 16 + lq][quad * 8];
  __syncthreads();                     // KsS consumed everywhere -> lis overlay safe
  if (t < 64) lis[t] = 1.0f / lg[(size_t)bh * Nq + t];
  __syncthreads();                     // lis[0] visible

  f32x4 ao[4];
#pragma unroll
  for (int nt = 0; nt < 4; nt++) ao[nt] = (f32x4){0.f, 0.f, 0.f, 0.f};

  const int ybase = lq + ((quad & 1) << 5);
  for (int qt2 = 0; qt2 < 16; qt2++) {
    if (qt2) __syncthreads();
    if (qt2 + 1 < 16) {
      stageQ(qt2 + 1, (qt2 + 1) & 1);
      if (t < 64)
        lis[((qt2 + 1) & 1) * 64 + t] = 1.0f / lg[(size_t)bh * Nq + (qt2 + 1) * 64 + t];
    }
    const int bi = qt2 & 1;
    f32x4 sc[4];
#pragma unroll
    for (int s = 0; s < 4; s++) sc[s] = (f32x4){0.f, 0.f, 0.f, 0.f};
#pragma unroll
    for (int zs = 0; zs < 2; zs++)
#pragma unroll
      for (int s = 0; s < 4; s++) {
        s16x8 a = *(const s16x8*)&Qs[bi][zs][s * 16 + lq][quad * 8];
        sc[s] = MFMA16(a, bkw[zs], sc[s], 0, 0, 0);
      }
    unsigned pw[4][2];
#pragma unroll
    for (int s = 0; s < 4; s++) {
      int qi = bi * 64 + s * 16 + quad * 4;
      float e0 = __expf(sc[s][0] * beta) * lis[qi + 0];
      float e1 = __expf(sc[s][1] * beta) * lis[qi + 1];
      float e2 = __expf(sc[s][2] * beta) * lis[qi + 2];
      float e3 = __expf(sc[s][3] * beta) * lis[qi + 3];
      pw[s][0] = pk2bf(e0, e1);
      pw[s][1] = pk2bf(e2, e3);
    }
#pragma unroll
    for (int m = 0; m < 2; m++) {
      union { unsigned u[4]; s16x8 v; } af;
#pragma unroll
      for (int p = 0; p < 4; p++) {
        int y = ybase + ((p >> 1) << 4);
        unsigned lo = (unsigned)__shfl((int)pw[2 * m][p & 1], y, 64);
        unsigned hi = (unsigned)__shfl((int)pw[2 * m + 1][p & 1], y, 64);
        af.u[p] = (quad < 2) ? lo : hi;
      }
#pragma unroll
      for (int nt = 0; nt < 4; nt++) {
        s16x8 bq = *(const s16x8*)&Qts[bi][m][nt * 16 + lq][quad * 8];
        ao[nt] = MFMA16(af.v, bq, ao[nt], 0, 0, 0);
      }
    }
  }
  u16* Oh = AV12 + (size_t)(b * Nq + k0) * QKP + Dq + h * 64;
#pragma unroll
  for (int nt = 0; nt < 4; nt++)
#pragma unroll
    for (int r = 0; r < 4; r++)
      Oh[(size_t)(w * 16 + quad * 4 + r) * QKP + nt * 16 + lq] = f2bf(ao[nt][r]);
}

// ---------------------------------------------------------------------------
extern "C" void kernel_launch(void* const* d_in, const int* in_sizes, int n_in,
                              void* d_out, int out_size, void* d_ws, size_t ws_size,
                              hipStream_t stream) {
  const float* x     = (const float*)d_in[0];
  const float* Wq    = (const float*)d_in[1];
  const float* Wk    = (const float*)d_in[2];
  const float* betas = (const float*)d_in[3];
  const float* Wm    = (const float*)d_in[4];
  float* out = (float*)d_out;

  // workspace layout (u16 units); ~93.4 MiB
  u16* xb   = (u16*)d_ws;                      // 6,291,456
  u16* Wqkb = xb + (size_t)BN * Dq;            // 1,179,648  [1536][768]
  u16* Wmb  = Wqkb + (size_t)QKP * Dq;         // 2,359,296  [3072][768]
  u16* WqkT = Wmb + (size_t)HIDq * Dq;         // 1,179,648  [768][1536]
  u16* QKb  = WqkT + (size_t)Dq * QKP;         // 12,582,912 [8192][1536]
  u16* QbT  = QKb + (size_t)BN * QKP;          // 6,291,456  [96][64][1024]
  u16* KbT  = QbT + (size_t)Bq * Hq * Zq * Nq; // 6,291,456
  u16* AV12 = KbT + (size_t)Bq * Hq * Zq * Nq; // 12,582,912 [8192][1536]
  float* lg = (float*)(AV12 + (size_t)BN * QKP);
  u16* hidb = QKb;   // overlays QKb/QbT/KbT (dead after attention)
  u16* WmT  = xb;    // overlays xb (dead after MLP1), [768][3072]

  dim3 blk(256);
  cvt2<<<8448, blk, 0, stream>>>(x, xb, Wm, Wmb);
  cvt_tr2<<<dim3(12, 12, 2), blk, 0, stream>>>(Wq, Wk, Wqkb, WqkT);

  // QK = x @ [Wq;Wk]^T  -> bf16 [8192][1536]
  gemm_bf16<false><<<dim3(QKP / 128, BN / 128), blk, 0, stream>>>(
      xb, Wqkb, QKb, BN, QKP, Dq);

  // per-head transposes of Q and K (single dispatch)
  head_tr<<<dim3(1, 16, 192), blk, 0, stream>>>(QKb, QbT, KbT);

  // attention
  attn_pass1<<<Bq * Hq * 16, blk, 0, stream>>>(QKb, KbT, betas, AV12, lg);
  attn_pass2<<<Bq * Hq * 16, blk, 0, stream>>>(QKb, QbT, betas, AV12, lg);

  // MLP up-proj: hid = relu(x @ Wm^T) bf16 (overlays QKb/QbT/KbT)
  gemm_bf16<true><<<dim3(HIDq / 128, BN / 128), blk, 0, stream>>>(
      xb, Wmb, hidb, BN, HIDq, Dq);

  // Wm transpose into xb region (xb dead after MLP1)
  transpose_bf16<<<dim3(12, 48, 1), blk, 0, stream>>>(Wmb, WmT, Dq, HIDq, 1, 0, 0, 0, 0);

  // out = AV12 @ WqkT^T + hid @ WmT^T, single dispatch, no atomics
  gemm_out2<<<dim3(Dq / 64, BN / 128), blk, 0, stream>>>(AV12, hidb, WqkT, WmT, out);
}

// Round 5
// 369.942 us; speedup vs baseline: 1.0249x; 1.0249x over previous
//
#include <hip/hip_runtime.h>
#include <hip/hip_bf16.h>

#define Bq 8
#define Nq 1024
#define Dq 768
#define Hq 12
#define Zq 64
#define HIDq 3072
#define BN (Bq*Nq)            // 8192
#define QKP 1536              // pitch of fused QK / AV12 buffers

typedef unsigned short u16;
typedef short s16x8 __attribute__((ext_vector_type(8)));
typedef float f32x4 __attribute__((ext_vector_type(4)));
typedef unsigned short u16x4 __attribute__((ext_vector_type(4)));

#define MFMA16 __builtin_amdgcn_mfma_f32_16x16x32_bf16
#define GLOAD16(g, l) __builtin_amdgcn_global_load_lds( \
    (const __attribute__((address_space(1))) void*)(const void*)(g), \
    (__attribute__((address_space(3))) void*)(l), 16, 0, 0)

__device__ __forceinline__ u16 f2bf(float f) {
  unsigned u = __float_as_uint(f);
  return (u16)((u + 0x7FFFu + ((u >> 16) & 1u)) >> 16);
}

// paired f32->bf16 (v_cvt_pk_bf16_f32; RNE, matches f2bf)
__device__ __forceinline__ unsigned pk2bf(float a, float b) {
  union { __hip_bfloat162 h; unsigned u; } cv;
  cv.h.x = __float2bfloat16(a);
  cv.h.y = __float2bfloat16(b);
  return cv.u;
}

// XCD-aware swizzle: all gx tiles of a row-panel (and gy/8 consecutive panels)
// land on one XCD (dispatch round-robins linear id % 8). Requires gy % 8 == 0.
__device__ __forceinline__ void xcd_swizzle(int gx, int gy, int& bx, int& by) {
  int l = blockIdx.y * gx + blockIdx.x;
  int c = l & 7, j = l >> 3;
  by = c * (gy >> 3) + j / gx;
  bx = j % gx;
}

// ---------------------------------------------------------------------------
// f32 -> bf16 convert, TWO tensors in one dispatch (x then Wm)
// blocks 0..6143 -> x (BN*Dq), 6144..8447 -> Wm (HIDq*Dq)
// ---------------------------------------------------------------------------
__global__ __launch_bounds__(256) void cvt2(const float* __restrict__ x, u16* __restrict__ xb,
                                            const float* __restrict__ Wm, u16* __restrict__ Wmb) {
  int bid = blockIdx.x;
  const float* in; u16* out; int i;
  if (bid < 6144) { in = x;  out = xb;  i = bid * 1024 + threadIdx.x * 4; }
  else            { in = Wm; out = Wmb; i = (bid - 6144) * 1024 + threadIdx.x * 4; }
  float4 v = *(const float4*)&in[i];
  u16x4 o; o[0] = f2bf(v.x); o[1] = f2bf(v.y); o[2] = f2bf(v.z); o[3] = f2bf(v.w);
  *(u16x4*)&out[i] = o;
}

// ---------------------------------------------------------------------------
// Wq/Wk f32 [768][768] -> bf16 [row-major into Wqkb slab] AND transposed into
// WqkT [768][1536]. grid (12, 12, 2): z=0 -> Wq, z=1 -> Wk.
// ---------------------------------------------------------------------------
__global__ __launch_bounds__(256) void cvt_tr2(const float* __restrict__ Wq,
                                               const float* __restrict__ Wk,
                                               u16* __restrict__ Wqkb,
                                               u16* __restrict__ WqkT) {
  __shared__ u16 T[64][72];
  const int t = threadIdx.x;
  const int z = blockIdx.z;
  const float* in = z ? Wk : Wq;
  u16* out = Wqkb + (size_t)z * Dq * Dq;
  u16* outT = WqkT + z * Dq;
  const int r0 = blockIdx.y * 64, c0 = blockIdx.x * 64;
  const int r = t >> 3, c8 = (t & 7) * 8;
#pragma unroll
  for (int p = 0; p < 2; p++) {
    const float* ip = &in[(size_t)(r0 + r + p * 32) * Dq + c0 + c8];
    float4 v0 = *(const float4*)ip, v1 = *(const float4*)(ip + 4);
    u16 tmp[8] = {f2bf(v0.x), f2bf(v0.y), f2bf(v0.z), f2bf(v0.w),
                  f2bf(v1.x), f2bf(v1.y), f2bf(v1.z), f2bf(v1.w)};
    *(uint4*)&out[(size_t)(r0 + r + p * 32) * Dq + c0 + c8] = *(uint4*)tmp;
    *(uint4*)&T[r + p * 32][c8] = *(uint4*)tmp;
  }
  __syncthreads();
#pragma unroll
  for (int p = 0; p < 2; p++) {
    int oc = r + p * 32;
    u16 tmp[8];
#pragma unroll
    for (int j = 0; j < 8; j++) tmp[j] = T[c8 + j][oc];
    *(uint4*)&outT[(size_t)(c0 + oc) * QKP + r0 + c8] = *(uint4*)tmp;
  }
}

// ---------------------------------------------------------------------------
// Batched 64x64-tiled bf16 transpose (used for WmT only).
// ---------------------------------------------------------------------------
__global__ __launch_bounds__(256) void transpose_bf16(
    const u16* __restrict__ in, u16* __restrict__ out,
    int in_pitch, int out_pitch, int inner_n,
    long in_bs_o, long in_bs_i, long out_bs_o, long out_bs_i) {
  __shared__ u16 T[64][72];
  const int t = threadIdx.x;
  const int bz = blockIdx.z;
  const long iboff = (long)(bz / inner_n) * in_bs_o + (long)(bz % inner_n) * in_bs_i;
  const long oboff = (long)(bz / inner_n) * out_bs_o + (long)(bz % inner_n) * out_bs_i;
  const u16* ip = in + iboff + (long)(blockIdx.y * 64) * in_pitch + blockIdx.x * 64;
  u16* op = out + oboff + (long)(blockIdx.x * 64) * out_pitch + blockIdx.y * 64;
  const int r = t >> 3, c8 = (t & 7) * 8;
#pragma unroll
  for (int p = 0; p < 2; p++)
    *(uint4*)&T[r + p * 32][c8] = *(const uint4*)(ip + (size_t)(r + p * 32) * in_pitch + c8);
  __syncthreads();
#pragma unroll
  for (int p = 0; p < 2; p++) {
    int oc = r + p * 32;
    u16 tmp[8];
#pragma unroll
    for (int j = 0; j < 8; j++) tmp[j] = T[c8 + j][oc];
    *(uint4*)(op + (size_t)oc * out_pitch + c8) = *(uint4*)tmp;
  }
}

// ---------------------------------------------------------------------------
// Per-head transposes of Q and K in ONE dispatch. grid (1, 16, 192):
// z 0..95 -> Q panel (cols 0:768 of QKb), z 96..191 -> K panel (cols 768:1536).
// ---------------------------------------------------------------------------
__global__ __launch_bounds__(256) void head_tr(const u16* __restrict__ QKb,
                                               u16* __restrict__ QbT,
                                               u16* __restrict__ KbT) {
  __shared__ u16 T[64][72];
  const int t = threadIdx.x;
  const int z = blockIdx.z;
  const int half = (z >= 96) ? 1 : 0;
  const int bhh = z - 96 * half;
  const u16* ip = QKb + (size_t)(bhh / Hq) * Nq * QKP + (bhh % Hq) * 64 + half * Dq
                + (size_t)(blockIdx.y * 64) * QKP;
  u16* op = (half ? KbT : QbT) + (size_t)bhh * 64 * Nq + blockIdx.y * 64;
  const int r = t >> 3, c8 = (t & 7) * 8;
#pragma unroll
  for (int p = 0; p < 2; p++)
    *(uint4*)&T[r + p * 32][c8] = *(const uint4*)(ip + (size_t)(r + p * 32) * QKP + c8);
  __syncthreads();
#pragma unroll
  for (int p = 0; p < 2; p++) {
    int oc = r + p * 32;
    u16 tmp[8];
#pragma unroll
    for (int j = 0; j < 8; j++) tmp[j] = T[c8 + j][oc];
    *(uint4*)(op + (size_t)oc * Nq + c8) = *(uint4*)tmp;
  }
}

// ---------------------------------------------------------------------------
// bf16 MFMA GEMM: C[M,N] = A[M,K] * B[N,K]^T, bf16 out. 128x128 tile, BK=32,
// double-buffered single-barrier pipeline. XCD-swizzled. LDS 32 KB.
// ---------------------------------------------------------------------------
template<bool RELU>
__global__ __launch_bounds__(256) void gemm_bf16(
    const u16* __restrict__ A, const u16* __restrict__ B, u16* __restrict__ C,
    int M, int N, int K) {
  __shared__ u16 As[2][128 * 32];
  __shared__ u16 Bs[2][128 * 32];
  int bx, by;
  xcd_swizzle(gridDim.x, gridDim.y, bx, by);
  const int t = threadIdx.x, l = t & 63, w = t >> 6;
  const int lq = l & 15, quad = l >> 4;
  const int bm = by * 128, bn = bx * 128;
  const int wm = (w & 1) * 64, wn = (w >> 1) * 64;
  f32x4 acc[4][4];
#pragma unroll
  for (int i = 0; i < 4; i++)
#pragma unroll
    for (int j = 0; j < 4; j++) acc[i][j] = (f32x4){0.f, 0.f, 0.f, 0.f};

  auto stage = [&](int k0, int bufi) {
#pragma unroll
    for (int p = 0; p < 2; p++) {
      int idx = p * 256 + t;
      GLOAD16(A + (size_t)(bm + (idx >> 2)) * K + k0 + (idx & 3) * 8, &As[bufi][idx * 8]);
      GLOAD16(B + (size_t)(bn + (idx >> 2)) * K + k0 + (idx & 3) * 8, &Bs[bufi][idx * 8]);
    }
  };
  stage(0, 0);
  const int nIter = K >> 5;
  for (int it = 0; it < nIter; it++) {
    __syncthreads();
    if (it + 1 < nIter) stage((it + 1) * 32, (it + 1) & 1);
    const int bi = it & 1;
    s16x8 af[4], bf[4];
#pragma unroll
    for (int mt = 0; mt < 4; mt++)
      af[mt] = *(const s16x8*)&As[bi][(wm + mt * 16 + lq) * 32 + quad * 8];
#pragma unroll
    for (int nt = 0; nt < 4; nt++)
      bf[nt] = *(const s16x8*)&Bs[bi][(wn + nt * 16 + lq) * 32 + quad * 8];
#pragma unroll
    for (int mt = 0; mt < 4; mt++)
#pragma unroll
      for (int nt = 0; nt < 4; nt++)
        acc[mt][nt] = MFMA16(af[mt], bf[nt], acc[mt][nt], 0, 0, 0);
  }
#pragma unroll
  for (int mt = 0; mt < 4; mt++)
#pragma unroll
    for (int nt = 0; nt < 4; nt++) {
      int row = bm + wm + mt * 16 + quad * 4;
      int col = bn + wn + nt * 16 + lq;
#pragma unroll
      for (int r = 0; r < 4; r++) {
        float v = acc[mt][nt][r];
        if (RELU) v = fmaxf(v, 0.f);
        C[(size_t)(row + r) * N + col] = f2bf(v);
      }
    }
}

// ---------------------------------------------------------------------------
// Fused output GEMM, COUNTED-VMCNT pipeline (T4): 128x64 tile of out[8192][768],
//   out = AV12[8192][1536] @ WqkT^T + hid[8192][3072] @ WmT^T
// BK=32 (144 tiles), THREE LDS buffers (36 KB -> 4 blocks/CU), prefetch
// distance 2 tiles (6 loads in flight). Per iteration:
//   s_waitcnt vmcnt(3)   // tile t's 3 loads landed (2 tiles x 3 in flight)
//   s_barrier            // raw: no vmcnt(0) drain -> tile t+1 stays in flight
//   sched_barrier(0)
//   stage(t+2)           // after barrier: buf[(t+2)%3]'s readers (iter t-1)
//                        // finished before the barrier (lgkm-dependency)
//   ds_read + 8 MFMA on buf[t%3]
// Each wave's own vmcnt<=3 before the barrier => after the rendezvous ALL
// waves' tile-t loads are visible. grid (12, 64) = 768 blocks, XCD-swizzled.
// ---------------------------------------------------------------------------
__global__ __launch_bounds__(256) void gemm_out2(
    const u16* __restrict__ AV12, const u16* __restrict__ hid,
    const u16* __restrict__ WqkT, const u16* __restrict__ WmT,
    float* __restrict__ out) {
  __shared__ u16 As[3][128 * 32];   // 24 KB
  __shared__ u16 Bs[3][64 * 32];    // 12 KB
  int bx, by;
  xcd_swizzle(gridDim.x, gridDim.y, bx, by);
  const int t = threadIdx.x, l = t & 63, w = t >> 6;
  const int lq = l & 15, quad = l >> 4;
  const int bm = by * 128, bn = bx * 64;
  const int wm = w * 32;
  f32x4 acc[2][4];
#pragma unroll
  for (int i = 0; i < 2; i++)
#pragma unroll
    for (int j = 0; j < 4; j++) acc[i][j] = (f32x4){0.f, 0.f, 0.f, 0.f};

  // tiles 0..47 = AV12/WqkT (K=1536), 48..143 = hid/WmT (K=3072)
  auto stage = [&](int tl, int bufi) {
    const u16* A; const u16* B; int pitch, k0;
    if (tl < 48) { A = AV12; B = WqkT; pitch = QKP;  k0 = tl * 32; }
    else         { A = hid;  B = WmT;  pitch = HIDq; k0 = (tl - 48) * 32; }
#pragma unroll
    for (int p = 0; p < 2; p++) {               // A: 128x32 = 512 x 16B
      int idx = p * 256 + t;
      GLOAD16(A + (size_t)(bm + (idx >> 2)) * pitch + k0 + (idx & 3) * 8,
              &As[bufi][idx * 8]);
    }
    GLOAD16(B + (size_t)(bn + (t >> 2)) * pitch + k0 + (t & 3) * 8,  // B: 64x32
            &Bs[bufi][t * 8]);
  };
  stage(0, 0);
  stage(1, 1);
  for (int tl = 0; tl < 144; tl++) {
    if (tl < 143) asm volatile("s_waitcnt vmcnt(3)" ::: "memory");
    else          asm volatile("s_waitcnt vmcnt(0)" ::: "memory");
    __builtin_amdgcn_s_barrier();
    __builtin_amdgcn_sched_barrier(0);
    if (tl + 2 < 144) stage(tl + 2, (tl + 2) % 3);
    const int bi = tl % 3;
    s16x8 af[2], bf[4];
#pragma unroll
    for (int mt = 0; mt < 2; mt++)
      af[mt] = *(const s16x8*)&As[bi][(wm + mt * 16 + lq) * 32 + quad * 8];
#pragma unroll
    for (int nt = 0; nt < 4; nt++)
      bf[nt] = *(const s16x8*)&Bs[bi][(nt * 16 + lq) * 32 + quad * 8];
#pragma unroll
    for (int mt = 0; mt < 2; mt++)
#pragma unroll
      for (int nt = 0; nt < 4; nt++)
        acc[mt][nt] = MFMA16(af[mt], bf[nt], acc[mt][nt], 0, 0, 0);
  }
#pragma unroll
  for (int mt = 0; mt < 2; mt++)
#pragma unroll
    for (int nt = 0; nt < 4; nt++) {
      int row = bm + wm + mt * 16 + quad * 4;
      int col = bn + nt * 16 + lq;
#pragma unroll
      for (int r = 0; r < 4; r++)
        out[(size_t)(row + r) * Dq + col] = acc[mt][nt][r];
    }
}

// ---------------------------------------------------------------------------
// Attention pass 1 (round-3 version, best measured). Per (b,h,64-q).
// P = exp(beta*S), l = sum_k, AV1 = (P/l) @ K via MFMA. Writes AV12[:,0:768], l.
// LDS-dieted pipeline (33 KB -> 4 blocks/CU): Qs overlaid on Ps; Ks
// single-buffered staged post-mid-barrier; Kts double-buffered; red/li
// overlay Kts post-loop. 2 barriers/iter.
// ---------------------------------------------------------------------------
__global__ __launch_bounds__(256) void attn_pass1(
    const u16* __restrict__ QKb, const u16* __restrict__ KbT,
    const float* __restrict__ betas, u16* __restrict__ AV12,
    float* __restrict__ lg) {
  __shared__ u16 Ps[64][72];         // 9216 B; first 4096 u16 double as Qs[2][64][32]
  __shared__ u16 Ks[2][64][32];      // 8 KB single-buffer [z-half][k-row][32]
  __shared__ u16 Kts[2][2][64][32];  // 16 KB dbuf [buf][k-half][z-row][32]

  const int t = threadIdx.x, l = t & 63, w = t >> 6;
  const int lq = l & 15, quad = l >> 4;
  const int c = blockIdx.x & 7, j = blockIdx.x >> 3;
  const int bh = c * 12 + j / 16, qt = j % 16;
  const int b = bh / Hq, h = bh % Hq;
  const int q0 = qt * 64;
  const float beta = betas[h];
  const u16* Qh = QKb + (size_t)(b * Nq) * QKP + h * 64;
  const u16* Kh = Qh + Dq;
  const u16* KTh = KbT + (size_t)bh * 64 * Nq;
  u16* QsF = &Ps[0][0];
  u16* KsF = &Ks[0][0][0];

  auto stageK = [&](int kt2) {
#pragma unroll
    for (int p = 0; p < 2; p++) {
      int idx = p * 256 + t;
      GLOAD16(Kh + (size_t)(kt2 * 64 + ((idx >> 2) & 63)) * QKP + (idx >> 8) * 32 + (idx & 3) * 8,
              KsF + idx * 8);
    }
  };
  auto stageKt = [&](int kt2, int bufi) {
#pragma unroll
    for (int p = 0; p < 2; p++) {
      int idx = p * 256 + t;
      GLOAD16(KTh + (size_t)((idx >> 2) & 63) * Nq + kt2 * 64 + (idx >> 8) * 32 + (idx & 3) * 8,
              &Kts[bufi][0][0][0] + idx * 8);
    }
  };

  // prologue: stage Q (into Ps region), K(0), Kt(0)
#pragma unroll
  for (int p = 0; p < 2; p++) {
    int idx = p * 256 + t;
    GLOAD16(Qh + (size_t)(q0 + ((idx >> 2) & 63)) * QKP + (idx >> 8) * 32 + (idx & 3) * 8,
            QsF + idx * 8);
  }
  stageK(0);
  stageKt(0, 0);
  __syncthreads();
  s16x8 bqf[2][4];
#pragma unroll
  for (int zs = 0; zs < 2; zs++)
#pragma unroll
    for (int nt = 0; nt < 4; nt++)
      bqf[zs][nt] = *(const s16x8*)&QsF[zs * 2048 + (nt * 16 + lq) * 32 + quad * 8];
  __syncthreads();                   // Qs consumed by ALL waves; Ps region free

  float lsum[4] = {0.f, 0.f, 0.f, 0.f};
  f32x4 ao[4];
#pragma unroll
  for (int nt = 0; nt < 4; nt++) ao[nt] = (f32x4){0.f, 0.f, 0.f, 0.f};

  for (int kt = 0; kt < 16; kt++) {
    if (kt) __syncthreads();         // top: Ks(kt), Kts[kt&1] landed; Ps consumed
    const int bi = kt & 1;
    // S^T tile: col q = nt*16+lq, row k = kt*64 + w*16 + quad*4 + r
    f32x4 sc[4];
#pragma unroll
    for (int nt = 0; nt < 4; nt++) sc[nt] = (f32x4){0.f, 0.f, 0.f, 0.f};
#pragma unroll
    for (int zs = 0; zs < 2; zs++) {
      s16x8 a = *(const s16x8*)&Ks[zs][w * 16 + lq][quad * 8];
#pragma unroll
      for (int nt = 0; nt < 4; nt++)
        sc[nt] = MFMA16(a, bqf[zs][nt], sc[nt], 0, 0, 0);
    }
#pragma unroll
    for (int nt = 0; nt < 4; nt++) {
      float e0 = __expf(sc[nt][0] * beta), e1 = __expf(sc[nt][1] * beta);
      float e2 = __expf(sc[nt][2] * beta), e3 = __expf(sc[nt][3] * beta);
      lsum[nt] += (e0 + e1) + (e2 + e3);
      uint2 pk; pk.x = pk2bf(e0, e1); pk.y = pk2bf(e2, e3);
      *(uint2*)&Ps[nt * 16 + lq][w * 16 + quad * 4] = pk;
    }
    __syncthreads();                 // mid: Ps visible; all Ks reads done
    if (kt + 1 < 16) {               // stage next tiles; drain at next top sync
      stageK(kt + 1);
      stageKt(kt + 1, (kt + 1) & 1);
    }
    // O[q][z] += P[q][k] * K[k][z]; B-frag reads Kt rows (z-major)
#pragma unroll
    for (int ks = 0; ks < 2; ks++) {
      s16x8 a = *(const s16x8*)&Ps[w * 16 + lq][ks * 32 + quad * 8];
#pragma unroll
      for (int nt = 0; nt < 4; nt++) {
        s16x8 bk = *(const s16x8*)&Kts[bi][ks][nt * 16 + lq][quad * 8];
        ao[nt] = MFMA16(a, bk, ao[nt], 0, 0, 0);
      }
    }
  }
  __syncthreads();                   // all PV reads done -> Kts overlay safe
  float* redp = (float*)&Kts[0][0][0][0];   // 256 f32
  float* lip  = redp + 256;                 // 64 f32
#pragma unroll
  for (int nt = 0; nt < 4; nt++) {
    float v = lsum[nt];
    v += __shfl_xor(v, 16, 64);
    v += __shfl_xor(v, 32, 64);
    if (l < 16) redp[w * 64 + nt * 16 + lq] = v;
  }
  __syncthreads();
  if (t < 64) {
    float s = redp[t] + redp[64 + t] + redp[128 + t] + redp[192 + t];
    lg[(size_t)bh * Nq + q0 + t] = s;
    lip[t] = 1.0f / s;
  }
  __syncthreads();
  u16* Oh = AV12 + (size_t)(b * Nq + q0) * QKP + h * 64;
  float lr[4];
#pragma unroll
  for (int r = 0; r < 4; r++) lr[r] = lip[w * 16 + quad * 4 + r];
#pragma unroll
  for (int nt = 0; nt < 4; nt++)
#pragma unroll
    for (int r = 0; r < 4; r++)
      Oh[(size_t)(w * 16 + quad * 4 + r) * QKP + nt * 16 + lq] = f2bf(ao[nt][r] * lr[r]);
}

// ---------------------------------------------------------------------------
// Attention pass 2 (round-3 version). Per (b,h,64-k). Recompute P from l,
// AV2[k,z] = sum_q P[q,k]/l[q] * Q[q,z]. Ks overlaid on Pts, Qs single-buffered
// (staged post-mid), Qts dbuf, li_s dbuf. ~34 KB -> 4 blocks/CU.
// ---------------------------------------------------------------------------
__global__ __launch_bounds__(256) void attn_pass2(
    const u16* __restrict__ QKb, const u16* __restrict__ QbT,
    const float* __restrict__ betas, u16* __restrict__ AV12,
    const float* __restrict__ lg) {
  __shared__ u16 Pts[64][72];        // 9216 B; first 4096 u16 double as Ks[2][64][32]
  __shared__ u16 Qs[2][64][32];      // 8 KB single-buffer [z-half][q-row][32]
  __shared__ u16 Qts[2][2][64][32];  // 16 KB dbuf [buf][q-half][z-row][32]
  __shared__ float li_s[2][64];

  const int t = threadIdx.x, l = t & 63, w = t >> 6;
  const int lq = l & 15, quad = l >> 4;
  const int c = blockIdx.x & 7, j = blockIdx.x >> 3;
  const int bh = c * 12 + j / 16, kt = j % 16;
  const int b = bh / Hq, h = bh % Hq;
  const int k0 = kt * 64;
  const float beta = betas[h];
  const u16* Qh = QKb + (size_t)(b * Nq) * QKP + h * 64;
  const u16* Kh = Qh + Dq;
  const u16* QTh = QbT + (size_t)bh * 64 * Nq;
  u16* KsF = &Pts[0][0];
  u16* QsF = &Qs[0][0][0];

  auto stageQ = [&](int qt2) {
#pragma unroll
    for (int p = 0; p < 2; p++) {
      int idx = p * 256 + t;
      GLOAD16(Qh + (size_t)(qt2 * 64 + ((idx >> 2) & 63)) * QKP + (idx >> 8) * 32 + (idx & 3) * 8,
              QsF + idx * 8);
    }
  };
  auto stageQt = [&](int qt2, int bufi) {
#pragma unroll
    for (int p = 0; p < 2; p++) {
      int idx = p * 256 + t;
      GLOAD16(QTh + (size_t)((idx >> 2) & 63) * Nq + qt2 * 64 + (idx >> 8) * 32 + (idx & 3) * 8,
              &Qts[bufi][0][0][0] + idx * 8);
    }
  };

  // prologue: stage K (into Pts region), Q(0), Qt(0), li(0)
#pragma unroll
  for (int p = 0; p < 2; p++) {
    int idx = p * 256 + t;
    GLOAD16(Kh + (size_t)(k0 + ((idx >> 2) & 63)) * QKP + (idx >> 8) * 32 + (idx & 3) * 8,
            KsF + idx * 8);
  }
  stageQ(0);
  stageQt(0, 0);
  if (t < 64) li_s[0][t] = 1.0f / lg[(size_t)bh * Nq + t];
  __syncthreads();
  s16x8 bkf[2][4];
#pragma unroll
  for (int zs = 0; zs < 2; zs++)
#pragma unroll
    for (int nt = 0; nt < 4; nt++)
      bkf[zs][nt] = *(const s16x8*)&KsF[zs * 2048 + (nt * 16 + lq) * 32 + quad * 8];
  __syncthreads();                   // Ks consumed by ALL waves; Pts region free

  f32x4 ao[4];
#pragma unroll
  for (int nt = 0; nt < 4; nt++) ao[nt] = (f32x4){0.f, 0.f, 0.f, 0.f};

  for (int qt = 0; qt < 16; qt++) {
    if (qt) __syncthreads();         // top: Qs(qt), Qts[qt&1], li_s[qt&1] landed
    const int bi = qt & 1;
    // S tile: col k = nt*16+lq, row q = qt*64 + w*16 + quad*4 + r
    f32x4 sc[4];
#pragma unroll
    for (int nt = 0; nt < 4; nt++) sc[nt] = (f32x4){0.f, 0.f, 0.f, 0.f};
#pragma unroll
    for (int zs = 0; zs < 2; zs++) {
      s16x8 a = *(const s16x8*)&Qs[zs][w * 16 + lq][quad * 8];
#pragma unroll
      for (int nt = 0; nt < 4; nt++)
        sc[nt] = MFMA16(a, bkf[zs][nt], sc[nt], 0, 0, 0);
    }
    float lr[4];
#pragma unroll
    for (int r = 0; r < 4; r++) lr[r] = li_s[bi][w * 16 + quad * 4 + r];
#pragma unroll
    for (int nt = 0; nt < 4; nt++) {
      float e0 = __expf(sc[nt][0] * beta) * lr[0];
      float e1 = __expf(sc[nt][1] * beta) * lr[1];
      float e2 = __expf(sc[nt][2] * beta) * lr[2];
      float e3 = __expf(sc[nt][3] * beta) * lr[3];
      uint2 pk; pk.x = pk2bf(e0, e1); pk.y = pk2bf(e2, e3);
      *(uint2*)&Pts[nt * 16 + lq][w * 16 + quad * 4] = pk;
    }
    __syncthreads();                 // mid: Pts visible; all Qs reads done
    if (qt + 1 < 16) {               // stage next; drain at next top sync
      stageQ(qt + 1);
      stageQt(qt + 1, (qt + 1) & 1);
      if (t < 64) li_s[(qt + 1) & 1][t] = 1.0f / lg[(size_t)bh * Nq + (qt + 1) * 64 + t];
    }
    // AV2[k][z] += P^T[k][q] * Q[q][z]; B-frag reads Qt rows (z-major)
#pragma unroll
    for (int qs = 0; qs < 2; qs++) {
      s16x8 a = *(const s16x8*)&Pts[w * 16 + lq][qs * 32 + quad * 8];
#pragma unroll
      for (int nt = 0; nt < 4; nt++) {
        s16x8 bq = *(const s16x8*)&Qts[bi][qs][nt * 16 + lq][quad * 8];
        ao[nt] = MFMA16(a, bq, ao[nt], 0, 0, 0);
      }
    }
  }
  u16* Oh = AV12 + (size_t)(b * Nq + k0) * QKP + Dq + h * 64;
#pragma unroll
  for (int nt = 0; nt < 4; nt++)
#pragma unroll
    for (int r = 0; r < 4; r++)
      Oh[(size_t)(w * 16 + quad * 4 + r) * QKP + nt * 16 + lq] = f2bf(ao[nt][r]);
}

// ---------------------------------------------------------------------------
extern "C" void kernel_launch(void* const* d_in, const int* in_sizes, int n_in,
                              void* d_out, int out_size, void* d_ws, size_t ws_size,
                              hipStream_t stream) {
  const float* x     = (const float*)d_in[0];
  const float* Wq    = (const float*)d_in[1];
  const float* Wk    = (const float*)d_in[2];
  const float* betas = (const float*)d_in[3];
  const float* Wm    = (const float*)d_in[4];
  float* out = (float*)d_out;

  // workspace layout (u16 units); ~93.4 MiB
  u16* xb   = (u16*)d_ws;                      // 6,291,456
  u16* Wqkb = xb + (size_t)BN * Dq;            // 1,179,648  [1536][768]
  u16* Wmb  = Wqkb + (size_t)QKP * Dq;         // 2,359,296  [3072][768]
  u16* WqkT = Wmb + (size_t)HIDq * Dq;         // 1,179,648  [768][1536]
  u16* QKb  = WqkT + (size_t)Dq * QKP;         // 12,582,912 [8192][1536]
  u16* QbT  = QKb + (size_t)BN * QKP;          // 6,291,456  [96][64][1024]
  u16* KbT  = QbT + (size_t)Bq * Hq * Zq * Nq; // 6,291,456
  u16* AV12 = KbT + (size_t)Bq * Hq * Zq * Nq; // 12,582,912 [8192][1536]
  float* lg = (float*)(AV12 + (size_t)BN * QKP);
  u16* hidb = QKb;   // overlays QKb/QbT/KbT (dead after attention)
  u16* WmT  = xb;    // overlays xb (dead after MLP1), [768][3072]

  dim3 blk(256);
  cvt2<<<8448, blk, 0, stream>>>(x, xb, Wm, Wmb);
  cvt_tr2<<<dim3(12, 12, 2), blk, 0, stream>>>(Wq, Wk, Wqkb, WqkT);

  // QK = x @ [Wq;Wk]^T  -> bf16 [8192][1536]
  gemm_bf16<false><<<dim3(QKP / 128, BN / 128), blk, 0, stream>>>(
      xb, Wqkb, QKb, BN, QKP, Dq);

  // per-head transposes of Q and K (single dispatch)
  head_tr<<<dim3(1, 16, 192), blk, 0, stream>>>(QKb, QbT, KbT);

  // attention
  attn_pass1<<<Bq * Hq * 16, blk, 0, stream>>>(QKb, KbT, betas, AV12, lg);
  attn_pass2<<<Bq * Hq * 16, blk, 0, stream>>>(QKb, QbT, betas, AV12, lg);

  // MLP up-proj: hid = relu(x @ Wm^T) bf16 (overlays QKb/QbT/KbT)
  gemm_bf16<true><<<dim3(HIDq / 128, BN / 128), blk, 0, stream>>>(
      xb, Wmb, hidb, BN, HIDq, Dq);

  // Wm transpose into xb region (xb dead after MLP1)
  transpose_bf16<<<dim3(12, 48, 1), blk, 0, stream>>>(Wmb, WmT, Dq, HIDq, 1, 0, 0, 0, 0);

  // out = AV12 @ WqkT^T + hid @ WmT^T, counted-vmcnt pipeline
  gemm_out2<<<dim3(Dq / 64, BN / 128), blk, 0, stream>>>(AV12, hidb, WqkT, WmT, out);
}

// Round 6
// 368.238 us; speedup vs baseline: 1.0296x; 1.0046x over previous
//
#include <hip/hip_runtime.h>
#include <hip/hip_bf16.h>

#define Bq 8
#define Nq 1024
#define Dq 768
#define Hq 12
#define Zq 64
#define HIDq 3072
#define BN (Bq*Nq)            // 8192
#define QKP 1536              // pitch of fused QK / AV12 buffers

typedef unsigned short u16;
typedef short s16x8 __attribute__((ext_vector_type(8)));
typedef float f32x4 __attribute__((ext_vector_type(4)));
typedef unsigned short u16x4 __attribute__((ext_vector_type(4)));

#define MFMA16 __builtin_amdgcn_mfma_f32_16x16x32_bf16
#define GLOAD16(g, l) __builtin_amdgcn_global_load_lds( \
    (const __attribute__((address_space(1))) void*)(const void*)(g), \
    (__attribute__((address_space(3))) void*)(l), 16, 0, 0)

__device__ __forceinline__ u16 f2bf(float f) {
  unsigned u = __float_as_uint(f);
  return (u16)((u + 0x7FFFu + ((u >> 16) & 1u)) >> 16);
}

// paired f32->bf16 (v_cvt_pk_bf16_f32; RNE, matches f2bf)
__device__ __forceinline__ unsigned pk2bf(float a, float b) {
  union { __hip_bfloat162 h; unsigned u; } cv;
  cv.h.x = __float2bfloat16(a);
  cv.h.y = __float2bfloat16(b);
  return cv.u;
}

// XCD-aware swizzle: all gx tiles of a row-panel (and gy/8 consecutive panels)
// land on one XCD (dispatch round-robins linear id % 8). Requires gy % 8 == 0.
__device__ __forceinline__ void xcd_swizzle(int gx, int gy, int& bx, int& by) {
  int l = blockIdx.y * gx + blockIdx.x;
  int c = l & 7, j = l >> 3;
  by = c * (gy >> 3) + j / gx;
  bx = j % gx;
}

// ---------------------------------------------------------------------------
// f32 -> bf16 convert, TWO tensors in one dispatch (x then Wm)
// blocks 0..6143 -> x (BN*Dq), 6144..8447 -> Wm (HIDq*Dq)
// ---------------------------------------------------------------------------
__global__ __launch_bounds__(256) void cvt2(const float* __restrict__ x, u16* __restrict__ xb,
                                            const float* __restrict__ Wm, u16* __restrict__ Wmb) {
  int bid = blockIdx.x;
  const float* in; u16* out; int i;
  if (bid < 6144) { in = x;  out = xb;  i = bid * 1024 + threadIdx.x * 4; }
  else            { in = Wm; out = Wmb; i = (bid - 6144) * 1024 + threadIdx.x * 4; }
  float4 v = *(const float4*)&in[i];
  u16x4 o; o[0] = f2bf(v.x); o[1] = f2bf(v.y); o[2] = f2bf(v.z); o[3] = f2bf(v.w);
  *(u16x4*)&out[i] = o;
}

// ---------------------------------------------------------------------------
// Wq/Wk f32 [768][768] -> bf16 [row-major into Wqkb slab] AND transposed into
// WqkT [768][1536]. grid (12, 12, 2): z=0 -> Wq, z=1 -> Wk.
// ---------------------------------------------------------------------------
__global__ __launch_bounds__(256) void cvt_tr2(const float* __restrict__ Wq,
                                               const float* __restrict__ Wk,
                                               u16* __restrict__ Wqkb,
                                               u16* __restrict__ WqkT) {
  __shared__ u16 T[64][72];
  const int t = threadIdx.x;
  const int z = blockIdx.z;
  const float* in = z ? Wk : Wq;
  u16* out = Wqkb + (size_t)z * Dq * Dq;
  u16* outT = WqkT + z * Dq;
  const int r0 = blockIdx.y * 64, c0 = blockIdx.x * 64;
  const int r = t >> 3, c8 = (t & 7) * 8;
#pragma unroll
  for (int p = 0; p < 2; p++) {
    const float* ip = &in[(size_t)(r0 + r + p * 32) * Dq + c0 + c8];
    float4 v0 = *(const float4*)ip, v1 = *(const float4*)(ip + 4);
    u16 tmp[8] = {f2bf(v0.x), f2bf(v0.y), f2bf(v0.z), f2bf(v0.w),
                  f2bf(v1.x), f2bf(v1.y), f2bf(v1.z), f2bf(v1.w)};
    *(uint4*)&out[(size_t)(r0 + r + p * 32) * Dq + c0 + c8] = *(uint4*)tmp;
    *(uint4*)&T[r + p * 32][c8] = *(uint4*)tmp;
  }
  __syncthreads();
#pragma unroll
  for (int p = 0; p < 2; p++) {
    int oc = r + p * 32;
    u16 tmp[8];
#pragma unroll
    for (int j = 0; j < 8; j++) tmp[j] = T[c8 + j][oc];
    *(uint4*)&outT[(size_t)(c0 + oc) * QKP + r0 + c8] = *(uint4*)tmp;
  }
}

// ---------------------------------------------------------------------------
// Batched 64x64-tiled bf16 transpose (used for WmT only).
// ---------------------------------------------------------------------------
__global__ __launch_bounds__(256) void transpose_bf16(
    const u16* __restrict__ in, u16* __restrict__ out,
    int in_pitch, int out_pitch, int inner_n,
    long in_bs_o, long in_bs_i, long out_bs_o, long out_bs_i) {
  __shared__ u16 T[64][72];
  const int t = threadIdx.x;
  const int bz = blockIdx.z;
  const long iboff = (long)(bz / inner_n) * in_bs_o + (long)(bz % inner_n) * in_bs_i;
  const long oboff = (long)(bz / inner_n) * out_bs_o + (long)(bz % inner_n) * out_bs_i;
  const u16* ip = in + iboff + (long)(blockIdx.y * 64) * in_pitch + blockIdx.x * 64;
  u16* op = out + oboff + (long)(blockIdx.x * 64) * out_pitch + blockIdx.y * 64;
  const int r = t >> 3, c8 = (t & 7) * 8;
#pragma unroll
  for (int p = 0; p < 2; p++)
    *(uint4*)&T[r + p * 32][c8] = *(const uint4*)(ip + (size_t)(r + p * 32) * in_pitch + c8);
  __syncthreads();
#pragma unroll
  for (int p = 0; p < 2; p++) {
    int oc = r + p * 32;
    u16 tmp[8];
#pragma unroll
    for (int j = 0; j < 8; j++) tmp[j] = T[c8 + j][oc];
    *(uint4*)(op + (size_t)oc * out_pitch + c8) = *(uint4*)tmp;
  }
}

// ---------------------------------------------------------------------------
// Per-head transposes of Q and K in ONE dispatch. grid (1, 16, 192):
// z 0..95 -> Q panel (cols 0:768 of QKb), z 96..191 -> K panel (cols 768:1536).
// ---------------------------------------------------------------------------
__global__ __launch_bounds__(256) void head_tr(const u16* __restrict__ QKb,
                                               u16* __restrict__ QbT,
                                               u16* __restrict__ KbT) {
  __shared__ u16 T[64][72];
  const int t = threadIdx.x;
  const int z = blockIdx.z;
  const int half = (z >= 96) ? 1 : 0;
  const int bhh = z - 96 * half;
  const u16* ip = QKb + (size_t)(bhh / Hq) * Nq * QKP + (bhh % Hq) * 64 + half * Dq
                + (size_t)(blockIdx.y * 64) * QKP;
  u16* op = (half ? KbT : QbT) + (size_t)bhh * 64 * Nq + blockIdx.y * 64;
  const int r = t >> 3, c8 = (t & 7) * 8;
#pragma unroll
  for (int p = 0; p < 2; p++)
    *(uint4*)&T[r + p * 32][c8] = *(const uint4*)(ip + (size_t)(r + p * 32) * QKP + c8);
  __syncthreads();
#pragma unroll
  for (int p = 0; p < 2; p++) {
    int oc = r + p * 32;
    u16 tmp[8];
#pragma unroll
    for (int j = 0; j < 8; j++) tmp[j] = T[c8 + j][oc];
    *(uint4*)(op + (size_t)oc * Nq + c8) = *(uint4*)tmp;
  }
}

// ---------------------------------------------------------------------------
// bf16 MFMA GEMM: C[M,N] = A[M,K] * B[N,K]^T, bf16 out. 128x128 tile, BK=32,
// double-buffered single-barrier pipeline. XCD-swizzled. LDS 32 KB.
// ---------------------------------------------------------------------------
template<bool RELU>
__global__ __launch_bounds__(256) void gemm_bf16(
    const u16* __restrict__ A, const u16* __restrict__ B, u16* __restrict__ C,
    int M, int N, int K) {
  __shared__ u16 As[2][128 * 32];
  __shared__ u16 Bs[2][128 * 32];
  int bx, by;
  xcd_swizzle(gridDim.x, gridDim.y, bx, by);
  const int t = threadIdx.x, l = t & 63, w = t >> 6;
  const int lq = l & 15, quad = l >> 4;
  const int bm = by * 128, bn = bx * 128;
  const int wm = (w & 1) * 64, wn = (w >> 1) * 64;
  f32x4 acc[4][4];
#pragma unroll
  for (int i = 0; i < 4; i++)
#pragma unroll
    for (int j = 0; j < 4; j++) acc[i][j] = (f32x4){0.f, 0.f, 0.f, 0.f};

  auto stage = [&](int k0, int bufi) {
#pragma unroll
    for (int p = 0; p < 2; p++) {
      int idx = p * 256 + t;
      GLOAD16(A + (size_t)(bm + (idx >> 2)) * K + k0 + (idx & 3) * 8, &As[bufi][idx * 8]);
      GLOAD16(B + (size_t)(bn + (idx >> 2)) * K + k0 + (idx & 3) * 8, &Bs[bufi][idx * 8]);
    }
  };
  stage(0, 0);
  const int nIter = K >> 5;
  for (int it = 0; it < nIter; it++) {
    __syncthreads();
    if (it + 1 < nIter) stage((it + 1) * 32, (it + 1) & 1);
    const int bi = it & 1;
    s16x8 af[4], bf[4];
#pragma unroll
    for (int mt = 0; mt < 4; mt++)
      af[mt] = *(const s16x8*)&As[bi][(wm + mt * 16 + lq) * 32 + quad * 8];
#pragma unroll
    for (int nt = 0; nt < 4; nt++)
      bf[nt] = *(const s16x8*)&Bs[bi][(wn + nt * 16 + lq) * 32 + quad * 8];
#pragma unroll
    for (int mt = 0; mt < 4; mt++)
#pragma unroll
      for (int nt = 0; nt < 4; nt++)
        acc[mt][nt] = MFMA16(af[mt], bf[nt], acc[mt][nt], 0, 0, 0);
  }
#pragma unroll
  for (int mt = 0; mt < 4; mt++)
#pragma unroll
    for (int nt = 0; nt < 4; nt++) {
      int row = bm + wm + mt * 16 + quad * 4;
      int col = bn + wn + nt * 16 + lq;
#pragma unroll
      for (int r = 0; r < 4; r++) {
        float v = acc[mt][nt][r];
        if (RELU) v = fmaxf(v, 0.f);
        C[(size_t)(row + r) * N + col] = f2bf(v);
      }
    }
}

// ---------------------------------------------------------------------------
// Fused output GEMM (no atomics, REVERTED to proven BK=64 form): 128x64 tile,
//   out = AV12[8192][1536] @ WqkT^T + hid[8192][3072] @ WmT^T
// BK=64 (72 tiles), double-buffered single-barrier pipeline. LDS 48 KB.
// grid (12, 64) = 768 blocks, XCD-swizzled. Measured 87-88 us across 3 rounds.
// ---------------------------------------------------------------------------
__global__ __launch_bounds__(256) void gemm_out2(
    const u16* __restrict__ AV12, const u16* __restrict__ hid,
    const u16* __restrict__ WqkT, const u16* __restrict__ WmT,
    float* __restrict__ out) {
  __shared__ u16 As[2][128 * 64];   // 32 KB
  __shared__ u16 Bs[2][64 * 64];    // 16 KB
  int bx, by;
  xcd_swizzle(gridDim.x, gridDim.y, bx, by);
  const int t = threadIdx.x, l = t & 63, w = t >> 6;
  const int lq = l & 15, quad = l >> 4;
  const int bm = by * 128, bn = bx * 64;
  const int wm = w * 32;
  f32x4 acc[2][4];
#pragma unroll
  for (int i = 0; i < 2; i++)
#pragma unroll
    for (int j = 0; j < 4; j++) acc[i][j] = (f32x4){0.f, 0.f, 0.f, 0.f};

  // tiles 0..23 = AV12/WqkT (K=1536), 24..71 = hid/WmT (K=3072)
  auto stage = [&](int tl, int bufi) {
    const u16* A; const u16* B; int pitch, k0;
    if (tl < 24) { A = AV12; B = WqkT; pitch = QKP;  k0 = tl * 64; }
    else         { A = hid;  B = WmT;  pitch = HIDq; k0 = (tl - 24) * 64; }
#pragma unroll
    for (int p = 0; p < 4; p++) {
      int idx = p * 256 + t, ks = idx >> 9, rem = idx & 511;
      GLOAD16(A + (size_t)(bm + (rem >> 2)) * pitch + k0 + ks * 32 + (rem & 3) * 8,
              &As[bufi][idx * 8]);
    }
#pragma unroll
    for (int p = 0; p < 2; p++) {
      int idx = p * 256 + t, ks = idx >> 8, rem = idx & 255;
      GLOAD16(B + (size_t)(bn + (rem >> 2)) * pitch + k0 + ks * 32 + (rem & 3) * 8,
              &Bs[bufi][idx * 8]);
    }
  };
  stage(0, 0);
  for (int tl = 0; tl < 72; tl++) {
    __syncthreads();
    if (tl + 1 < 72) stage(tl + 1, (tl + 1) & 1);
    const int bi = tl & 1;
#pragma unroll
    for (int ks = 0; ks < 2; ks++) {
      s16x8 af[2], bf[4];
#pragma unroll
      for (int mt = 0; mt < 2; mt++)
        af[mt] = *(const s16x8*)&As[bi][ks * 4096 + (wm + mt * 16 + lq) * 32 + quad * 8];
#pragma unroll
      for (int nt = 0; nt < 4; nt++)
        bf[nt] = *(const s16x8*)&Bs[bi][ks * 2048 + (nt * 16 + lq) * 32 + quad * 8];
#pragma unroll
      for (int mt = 0; mt < 2; mt++)
#pragma unroll
        for (int nt = 0; nt < 4; nt++)
          acc[mt][nt] = MFMA16(af[mt], bf[nt], acc[mt][nt], 0, 0, 0);
    }
  }
#pragma unroll
  for (int mt = 0; mt < 2; mt++)
#pragma unroll
    for (int nt = 0; nt < 4; nt++) {
      int row = bm + wm + mt * 16 + quad * 4;
      int col = bn + nt * 16 + lq;
#pragma unroll
      for (int r = 0; r < 4; r++)
        out[(size_t)(row + r) * Dq + col] = acc[mt][nt][r];
    }
}

// ---------------------------------------------------------------------------
// Attention pass 1, QBLK=128. Per (b,h,128-q) block; grid 768 (= 3 blocks/CU).
// Wave w owns k-strip w*16..w*16+15 for S^T, q-rows w*32..w*32+31 for PV.
// Per kt iteration (same round-3 2-barrier pipeline, 2x MFMA per barrier):
//   S^T: sc[nt] = S^T[k=w*16+quad*4+r][q=nt*16+lq], nt = 0..7 (two groups of 4)
//   exp -> Ps[128][72]; lsum[8] per-lane partials
//   mid barrier; stage K/Kt(kt+1); PV: ao[half][nt] over q=w*32+half*16+...
// LDS: Ps 18.4K (first 16K doubles as Q staging) + Ks 8K single + Kts 16K dbuf
// = 43 KB -> 3 blocks/CU. Target VGPR <= 168 for 3 waves/SIMD.
// ---------------------------------------------------------------------------
__global__ __launch_bounds__(256) void attn_pass1(
    const u16* __restrict__ QKb, const u16* __restrict__ KbT,
    const float* __restrict__ betas, u16* __restrict__ AV12,
    float* __restrict__ lg) {
  __shared__ u16 Ps[128][72];        // 18,432 B; first 8192 u16 = Qs[2][128][32]
  __shared__ u16 Ks[2][64][32];      // 8 KB single-buffer [z-half][k-row][32]
  __shared__ u16 Kts[2][2][64][32];  // 16 KB dbuf [buf][k-half][z-row][32]

  const int t = threadIdx.x, l = t & 63, w = t >> 6;
  const int lq = l & 15, quad = l >> 4;
  const int c = blockIdx.x & 7, j = blockIdx.x >> 3;
  const int bh = c * 12 + j / 8, qt = j % 8;
  const int b = bh / Hq, h = bh % Hq;
  const int q0 = qt * 128;
  const float beta = betas[h];
  const u16* Qh = QKb + (size_t)(b * Nq) * QKP + h * 64;
  const u16* Kh = Qh + Dq;
  const u16* KTh = KbT + (size_t)bh * 64 * Nq;
  u16* QsF = &Ps[0][0];
  u16* KsF = &Ks[0][0][0];

  auto stageK = [&](int kt2) {
#pragma unroll
    for (int p = 0; p < 2; p++) {
      int idx = p * 256 + t;
      GLOAD16(Kh + (size_t)(kt2 * 64 + ((idx >> 2) & 63)) * QKP + (idx >> 8) * 32 + (idx & 3) * 8,
              KsF + idx * 8);
    }
  };
  auto stageKt = [&](int kt2, int bufi) {
#pragma unroll
    for (int p = 0; p < 2; p++) {
      int idx = p * 256 + t;
      GLOAD16(KTh + (size_t)((idx >> 2) & 63) * Nq + kt2 * 64 + (idx >> 8) * 32 + (idx & 3) * 8,
              &Kts[bufi][0][0][0] + idx * 8);
    }
  };

  // prologue: stage Q (128x64, into Ps region), K(0), Kt(0)
#pragma unroll
  for (int p = 0; p < 4; p++) {
    int idx = p * 256 + t;
    GLOAD16(Qh + (size_t)(q0 + ((idx >> 2) & 127)) * QKP + (idx >> 9) * 32 + (idx & 3) * 8,
            QsF + idx * 8);
  }
  stageK(0);
  stageKt(0, 0);
  __syncthreads();
  s16x8 bqf[2][8];
#pragma unroll
  for (int zs = 0; zs < 2; zs++)
#pragma unroll
    for (int nt = 0; nt < 8; nt++)
      bqf[zs][nt] = *(const s16x8*)&QsF[zs * 4096 + (nt * 16 + lq) * 32 + quad * 8];
  __syncthreads();                   // Qs consumed by ALL waves; Ps region free

  float lsum[8];
#pragma unroll
  for (int i = 0; i < 8; i++) lsum[i] = 0.f;
  f32x4 ao[2][4];
#pragma unroll
  for (int hf = 0; hf < 2; hf++)
#pragma unroll
    for (int nt = 0; nt < 4; nt++) ao[hf][nt] = (f32x4){0.f, 0.f, 0.f, 0.f};

  for (int kt = 0; kt < 16; kt++) {
    if (kt) __syncthreads();         // top: Ks(kt), Kts[kt&1] landed; Ps consumed
    const int bi = kt & 1;
    // S^T in two nt-groups of 4 (caps sc live range)
#pragma unroll
    for (int g = 0; g < 2; g++) {
      f32x4 sc[4];
#pragma unroll
      for (int j4 = 0; j4 < 4; j4++) sc[j4] = (f32x4){0.f, 0.f, 0.f, 0.f};
#pragma unroll
      for (int zs = 0; zs < 2; zs++) {
        s16x8 a = *(const s16x8*)&Ks[zs][w * 16 + lq][quad * 8];
#pragma unroll
        for (int j4 = 0; j4 < 4; j4++)
          sc[j4] = MFMA16(a, bqf[zs][g * 4 + j4], sc[j4], 0, 0, 0);
      }
#pragma unroll
      for (int j4 = 0; j4 < 4; j4++) {
        float e0 = __expf(sc[j4][0] * beta), e1 = __expf(sc[j4][1] * beta);
        float e2 = __expf(sc[j4][2] * beta), e3 = __expf(sc[j4][3] * beta);
        lsum[g * 4 + j4] += (e0 + e1) + (e2 + e3);
        uint2 pk; pk.x = pk2bf(e0, e1); pk.y = pk2bf(e2, e3);
        *(uint2*)&Ps[(g * 4 + j4) * 16 + lq][w * 16 + quad * 4] = pk;
      }
    }
    __syncthreads();                 // mid: Ps visible; all Ks reads done
    if (kt + 1 < 16) {               // stage next tiles; drain at next top sync
      stageK(kt + 1);
      stageKt(kt + 1, (kt + 1) & 1);
    }
    // O[q][z] += P[q][k] * K[k][z]; A rows = q (w*32+half*16+lq), B = Kt z-rows
#pragma unroll
    for (int ks = 0; ks < 2; ks++) {
      s16x8 bk[4];
#pragma unroll
      for (int nt = 0; nt < 4; nt++)
        bk[nt] = *(const s16x8*)&Kts[bi][ks][nt * 16 + lq][quad * 8];
#pragma unroll
      for (int hf = 0; hf < 2; hf++) {
        s16x8 a = *(const s16x8*)&Ps[w * 32 + hf * 16 + lq][ks * 32 + quad * 8];
#pragma unroll
        for (int nt = 0; nt < 4; nt++)
          ao[hf][nt] = MFMA16(a, bk[nt], ao[hf][nt], 0, 0, 0);
      }
    }
  }
  __syncthreads();                   // all PV reads done -> Kts overlay safe
  float* redp = (float*)&Kts[0][0][0][0];   // 512 f32
  float* lip  = redp + 512;                 // 128 f32
#pragma unroll
  for (int nt = 0; nt < 8; nt++) {
    float v = lsum[nt];
    v += __shfl_xor(v, 16, 64);
    v += __shfl_xor(v, 32, 64);
    if (l < 16) redp[w * 128 + nt * 16 + lq] = v;
  }
  __syncthreads();
  if (t < 128) {
    float s = redp[t] + redp[128 + t] + redp[256 + t] + redp[384 + t];
    lg[(size_t)bh * Nq + q0 + t] = s;
    lip[t] = 1.0f / s;
  }
  __syncthreads();
  u16* Oh = AV12 + (size_t)(b * Nq + q0) * QKP + h * 64;
#pragma unroll
  for (int hf = 0; hf < 2; hf++) {
    float lr[4];
#pragma unroll
    for (int r = 0; r < 4; r++) lr[r] = lip[w * 32 + hf * 16 + quad * 4 + r];
#pragma unroll
    for (int nt = 0; nt < 4; nt++)
#pragma unroll
      for (int r = 0; r < 4; r++)
        Oh[(size_t)(w * 32 + hf * 16 + quad * 4 + r) * QKP + nt * 16 + lq] =
            f2bf(ao[hf][nt][r] * lr[r]);
  }
}

// ---------------------------------------------------------------------------
// Attention pass 2, KBLK=128. Per (b,h,128-k) block; grid 768.
// Wave w: q-strip w*16..+15 for S, k-rows w*32..+31 for PV output.
// sc[nt] = S[q=w*16+quad*4+r][k=nt*16+lq], nt=0..7; P normalized by 1/l[q]
// in-register, packed to Pts[128][72]; PV B = Qt z-rows. Same 2-barrier
// pipeline: Qs single (staged post-mid), Qts dbuf, li_s dbuf.
// LDS: Pts 18.4K (first 16K = K staging) + Qs 8K + Qts 16K + li 0.5K = 43.5 KB.
// ---------------------------------------------------------------------------
__global__ __launch_bounds__(256) void attn_pass2(
    const u16* __restrict__ QKb, const u16* __restrict__ QbT,
    const float* __restrict__ betas, u16* __restrict__ AV12,
    const float* __restrict__ lg) {
  __shared__ u16 Pts[128][72];       // 18,432 B; first 8192 u16 = KsS[2][128][32]
  __shared__ u16 Qs[2][64][32];      // 8 KB single-buffer [z-half][q-row][32]
  __shared__ u16 Qts[2][2][64][32];  // 16 KB dbuf [buf][q-half][z-row][32]
  __shared__ float li_s[2][64];

  const int t = threadIdx.x, l = t & 63, w = t >> 6;
  const int lq = l & 15, quad = l >> 4;
  const int c = blockIdx.x & 7, j = blockIdx.x >> 3;
  const int bh = c * 12 + j / 8, kt = j % 8;
  const int b = bh / Hq, h = bh % Hq;
  const int k0 = kt * 128;
  const float beta = betas[h];
  const u16* Qh = QKb + (size_t)(b * Nq) * QKP + h * 64;
  const u16* Kh = Qh + Dq;
  const u16* QTh = QbT + (size_t)bh * 64 * Nq;
  u16* KsF = &Pts[0][0];
  u16* QsF = &Qs[0][0][0];

  auto stageQ = [&](int qt2) {
#pragma unroll
    for (int p = 0; p < 2; p++) {
      int idx = p * 256 + t;
      GLOAD16(Qh + (size_t)(qt2 * 64 + ((idx >> 2) & 63)) * QKP + (idx >> 8) * 32 + (idx & 3) * 8,
              QsF + idx * 8);
    }
  };
  auto stageQt = [&](int qt2, int bufi) {
#pragma unroll
    for (int p = 0; p < 2; p++) {
      int idx = p * 256 + t;
      GLOAD16(QTh + (size_t)((idx >> 2) & 63) * Nq + qt2 * 64 + (idx >> 8) * 32 + (idx & 3) * 8,
              &Qts[bufi][0][0][0] + idx * 8);
    }
  };

  // prologue: stage K (128x64, into Pts region), Q(0), Qt(0), li(0)
#pragma unroll
  for (int p = 0; p < 4; p++) {
    int idx = p * 256 + t;
    GLOAD16(Kh + (size_t)(k0 + ((idx >> 2) & 127)) * QKP + (idx >> 9) * 32 + (idx & 3) * 8,
            KsF + idx * 8);
  }
  stageQ(0);
  stageQt(0, 0);
  if (t < 64) li_s[0][t] = 1.0f / lg[(size_t)bh * Nq + t];
  __syncthreads();
  s16x8 bkf[2][8];
#pragma unroll
  for (int zs = 0; zs < 2; zs++)
#pragma unroll
    for (int nt = 0; nt < 8; nt++)
      bkf[zs][nt] = *(const s16x8*)&KsF[zs * 4096 + (nt * 16 + lq) * 32 + quad * 8];
  __syncthreads();                   // K consumed by ALL waves; Pts region free

  f32x4 ao[2][4];
#pragma unroll
  for (int hf = 0; hf < 2; hf++)
#pragma unroll
    for (int nt = 0; nt < 4; nt++) ao[hf][nt] = (f32x4){0.f, 0.f, 0.f, 0.f};

  for (int qt2 = 0; qt2 < 16; qt2++) {
    if (qt2) __syncthreads();        // top: Qs(qt2), Qts[bi], li_s[bi] landed
    const int bi = qt2 & 1;
    float lr[4];
#pragma unroll
    for (int r = 0; r < 4; r++) lr[r] = li_s[bi][w * 16 + quad * 4 + r];
#pragma unroll
    for (int g = 0; g < 2; g++) {
      f32x4 sc[4];
#pragma unroll
      for (int j4 = 0; j4 < 4; j4++) sc[j4] = (f32x4){0.f, 0.f, 0.f, 0.f};
#pragma unroll
      for (int zs = 0; zs < 2; zs++) {
        s16x8 a = *(const s16x8*)&Qs[zs][w * 16 + lq][quad * 8];
#pragma unroll
        for (int j4 = 0; j4 < 4; j4++)
          sc[j4] = MFMA16(a, bkf[zs][g * 4 + j4], sc[j4], 0, 0, 0);
      }
#pragma unroll
      for (int j4 = 0; j4 < 4; j4++) {
        float e0 = __expf(sc[j4][0] * beta) * lr[0];
        float e1 = __expf(sc[j4][1] * beta) * lr[1];
        float e2 = __expf(sc[j4][2] * beta) * lr[2];
        float e3 = __expf(sc[j4][3] * beta) * lr[3];
        uint2 pk; pk.x = pk2bf(e0, e1); pk.y = pk2bf(e2, e3);
        *(uint2*)&Pts[(g * 4 + j4) * 16 + lq][w * 16 + quad * 4] = pk;
      }
    }
    __syncthreads();                 // mid: Pts visible; all Qs reads done
    if (qt2 + 1 < 16) {              // stage next; drain at next top sync
      stageQ(qt2 + 1);
      stageQt(qt2 + 1, (qt2 + 1) & 1);
      if (t < 64) li_s[(qt2 + 1) & 1][t] = 1.0f / lg[(size_t)bh * Nq + (qt2 + 1) * 64 + t];
    }
    // AV2[k][z] += P^T[k][q] * Q[q][z]; A rows = k (w*32+half*16+lq)
#pragma unroll
    for (int qs = 0; qs < 2; qs++) {
      s16x8 bq[4];
#pragma unroll
      for (int nt = 0; nt < 4; nt++)
        bq[nt] = *(const s16x8*)&Qts[bi][qs][nt * 16 + lq][quad * 8];
#pragma unroll
      for (int hf = 0; hf < 2; hf++) {
        s16x8 a = *(const s16x8*)&Pts[w * 32 + hf * 16 + lq][qs * 32 + quad * 8];
#pragma unroll
        for (int nt = 0; nt < 4; nt++)
          ao[hf][nt] = MFMA16(a, bq[nt], ao[hf][nt], 0, 0, 0);
      }
    }
  }
  u16* Oh = AV12 + (size_t)(b * Nq + k0) * QKP + Dq + h * 64;
#pragma unroll
  for (int hf = 0; hf < 2; hf++)
#pragma unroll
    for (int nt = 0; nt < 4; nt++)
#pragma unroll
      for (int r = 0; r < 4; r++)
        Oh[(size_t)(w * 32 + hf * 16 + quad * 4 + r) * QKP + nt * 16 + lq] =
            f2bf(ao[hf][nt][r]);
}

// ---------------------------------------------------------------------------
extern "C" void kernel_launch(void* const* d_in, const int* in_sizes, int n_in,
                              void* d_out, int out_size, void* d_ws, size_t ws_size,
                              hipStream_t stream) {
  const float* x     = (const float*)d_in[0];
  const float* Wq    = (const float*)d_in[1];
  const float* Wk    = (const float*)d_in[2];
  const float* betas = (const float*)d_in[3];
  const float* Wm    = (const float*)d_in[4];
  float* out = (float*)d_out;

  // workspace layout (u16 units); ~93.4 MiB
  u16* xb   = (u16*)d_ws;                      // 6,291,456
  u16* Wqkb = xb + (size_t)BN * Dq;            // 1,179,648  [1536][768]
  u16* Wmb  = Wqkb + (size_t)QKP * Dq;         // 2,359,296  [3072][768]
  u16* WqkT = Wmb + (size_t)HIDq * Dq;         // 1,179,648  [768][1536]
  u16* QKb  = WqkT + (size_t)Dq * QKP;         // 12,582,912 [8192][1536]
  u16* QbT  = QKb + (size_t)BN * QKP;          // 6,291,456  [96][64][1024]
  u16* KbT  = QbT + (size_t)Bq * Hq * Zq * Nq; // 6,291,456
  u16* AV12 = KbT + (size_t)Bq * Hq * Zq * Nq; // 12,582,912 [8192][1536]
  float* lg = (float*)(AV12 + (size_t)BN * QKP);
  u16* hidb = QKb;   // overlays QKb/QbT/KbT (dead after attention)
  u16* WmT  = xb;    // overlays xb (dead after MLP1), [768][3072]

  dim3 blk(256);
  cvt2<<<8448, blk, 0, stream>>>(x, xb, Wm, Wmb);
  cvt_tr2<<<dim3(12, 12, 2), blk, 0, stream>>>(Wq, Wk, Wqkb, WqkT);

  // QK = x @ [Wq;Wk]^T  -> bf16 [8192][1536]
  gemm_bf16<false><<<dim3(QKP / 128, BN / 128), blk, 0, stream>>>(
      xb, Wqkb, QKb, BN, QKP, Dq);

  // per-head transposes of Q and K (single dispatch)
  head_tr<<<dim3(1, 16, 192), blk, 0, stream>>>(QKb, QbT, KbT);

  // attention (QBLK/KBLK = 128, 768 blocks each)
  attn_pass1<<<Bq * Hq * 8, blk, 0, stream>>>(QKb, KbT, betas, AV12, lg);
  attn_pass2<<<Bq * Hq * 8, blk, 0, stream>>>(QKb, QbT, betas, AV12, lg);

  // MLP up-proj: hid = relu(x @ Wm^T) bf16 (overlays QKb/QbT/KbT)
  gemm_bf16<true><<<dim3(HIDq / 128, BN / 128), blk, 0, stream>>>(
      xb, Wmb, hidb, BN, HIDq, Dq);

  // Wm transpose into xb region (xb dead after MLP1)
  transpose_bf16<<<dim3(12, 48, 1), blk, 0, stream>>>(Wmb, WmT, Dq, HIDq, 1, 0, 0, 0, 0);

  // out = AV12 @ WqkT^T + hid @ WmT^T, single dispatch, no atomics
  gemm_out2<<<dim3(Dq / 64, BN / 128), blk, 0, stream>>>(AV12, hidb, WqkT, WmT, out);
}

// Round 7
// 353.365 us; speedup vs baseline: 1.0730x; 1.0421x over previous
//
#include <hip/hip_runtime.h>
#include <hip/hip_bf16.h>

#define Bq 8
#define Nq 1024
#define Dq 768
#define Hq 12
#define Zq 64
#define HIDq 3072
#define BN (Bq*Nq)            // 8192
#define QKP 1536              // pitch of fused QK / AV12 buffers

typedef unsigned short u16;
typedef short s16x8 __attribute__((ext_vector_type(8)));
typedef float f32x4 __attribute__((ext_vector_type(4)));
typedef unsigned short u16x4 __attribute__((ext_vector_type(4)));

#define MFMA16 __builtin_amdgcn_mfma_f32_16x16x32_bf16
#define GLOAD16(g, l) __builtin_amdgcn_global_load_lds( \
    (const __attribute__((address_space(1))) void*)(const void*)(g), \
    (__attribute__((address_space(3))) void*)(l), 16, 0, 0)

__device__ __forceinline__ u16 f2bf(float f) {
  unsigned u = __float_as_uint(f);
  return (u16)((u + 0x7FFFu + ((u >> 16) & 1u)) >> 16);
}

// paired f32->bf16 (v_cvt_pk_bf16_f32; RNE, matches f2bf)
__device__ __forceinline__ unsigned pk2bf(float a, float b) {
  union { __hip_bfloat162 h; unsigned u; } cv;
  cv.h.x = __float2bfloat16(a);
  cv.h.y = __float2bfloat16(b);
  return cv.u;
}

// XCD-aware swizzle: all gx tiles of a row-panel (and gy/8 consecutive panels)
// land on one XCD (dispatch round-robins linear id % 8). Requires gy % 8 == 0.
__device__ __forceinline__ void xcd_swizzle(int gx, int gy, int& bx, int& by) {
  int l = blockIdx.y * gx + blockIdx.x;
  int c = l & 7, j = l >> 3;
  by = c * (gy >> 3) + j / gx;
  bx = j % gx;
}

// ---------------------------------------------------------------------------
// f32 -> bf16 convert, TWO tensors in one dispatch (x then Wm)
// blocks 0..6143 -> x (BN*Dq), 6144..8447 -> Wm (HIDq*Dq)
// ---------------------------------------------------------------------------
__global__ __launch_bounds__(256) void cvt2(const float* __restrict__ x, u16* __restrict__ xb,
                                            const float* __restrict__ Wm, u16* __restrict__ Wmb) {
  int bid = blockIdx.x;
  const float* in; u16* out; int i;
  if (bid < 6144) { in = x;  out = xb;  i = bid * 1024 + threadIdx.x * 4; }
  else            { in = Wm; out = Wmb; i = (bid - 6144) * 1024 + threadIdx.x * 4; }
  float4 v = *(const float4*)&in[i];
  u16x4 o; o[0] = f2bf(v.x); o[1] = f2bf(v.y); o[2] = f2bf(v.z); o[3] = f2bf(v.w);
  *(u16x4*)&out[i] = o;
}

// ---------------------------------------------------------------------------
// Wq/Wk f32 [768][768] -> bf16 [row-major into Wqkb slab] AND transposed into
// WqkT [768][1536]. grid (12, 12, 2): z=0 -> Wq, z=1 -> Wk.
// ---------------------------------------------------------------------------
__global__ __launch_bounds__(256) void cvt_tr2(const float* __restrict__ Wq,
                                               const float* __restrict__ Wk,
                                               u16* __restrict__ Wqkb,
                                               u16* __restrict__ WqkT) {
  __shared__ u16 T[64][72];
  const int t = threadIdx.x;
  const int z = blockIdx.z;
  const float* in = z ? Wk : Wq;
  u16* out = Wqkb + (size_t)z * Dq * Dq;
  u16* outT = WqkT + z * Dq;
  const int r0 = blockIdx.y * 64, c0 = blockIdx.x * 64;
  const int r = t >> 3, c8 = (t & 7) * 8;
#pragma unroll
  for (int p = 0; p < 2; p++) {
    const float* ip = &in[(size_t)(r0 + r + p * 32) * Dq + c0 + c8];
    float4 v0 = *(const float4*)ip, v1 = *(const float4*)(ip + 4);
    u16 tmp[8] = {f2bf(v0.x), f2bf(v0.y), f2bf(v0.z), f2bf(v0.w),
                  f2bf(v1.x), f2bf(v1.y), f2bf(v1.z), f2bf(v1.w)};
    *(uint4*)&out[(size_t)(r0 + r + p * 32) * Dq + c0 + c8] = *(uint4*)tmp;
    *(uint4*)&T[r + p * 32][c8] = *(uint4*)tmp;
  }
  __syncthreads();
#pragma unroll
  for (int p = 0; p < 2; p++) {
    int oc = r + p * 32;
    u16 tmp[8];
#pragma unroll
    for (int j = 0; j < 8; j++) tmp[j] = T[c8 + j][oc];
    *(uint4*)&outT[(size_t)(c0 + oc) * QKP + r0 + c8] = *(uint4*)tmp;
  }
}

// ---------------------------------------------------------------------------
// Batched 64x64-tiled bf16 transpose (used for WmT only).
// ---------------------------------------------------------------------------
__global__ __launch_bounds__(256) void transpose_bf16(
    const u16* __restrict__ in, u16* __restrict__ out,
    int in_pitch, int out_pitch, int inner_n,
    long in_bs_o, long in_bs_i, long out_bs_o, long out_bs_i) {
  __shared__ u16 T[64][72];
  const int t = threadIdx.x;
  const int bz = blockIdx.z;
  const long iboff = (long)(bz / inner_n) * in_bs_o + (long)(bz % inner_n) * in_bs_i;
  const long oboff = (long)(bz / inner_n) * out_bs_o + (long)(bz % inner_n) * out_bs_i;
  const u16* ip = in + iboff + (long)(blockIdx.y * 64) * in_pitch + blockIdx.x * 64;
  u16* op = out + oboff + (long)(blockIdx.x * 64) * out_pitch + blockIdx.y * 64;
  const int r = t >> 3, c8 = (t & 7) * 8;
#pragma unroll
  for (int p = 0; p < 2; p++)
    *(uint4*)&T[r + p * 32][c8] = *(const uint4*)(ip + (size_t)(r + p * 32) * in_pitch + c8);
  __syncthreads();
#pragma unroll
  for (int p = 0; p < 2; p++) {
    int oc = r + p * 32;
    u16 tmp[8];
#pragma unroll
    for (int j = 0; j < 8; j++) tmp[j] = T[c8 + j][oc];
    *(uint4*)(op + (size_t)oc * out_pitch + c8) = *(uint4*)tmp;
  }
}

// ---------------------------------------------------------------------------
// Per-head transposes of Q and K in ONE dispatch. grid (1, 16, 192):
// z 0..95 -> Q panel (cols 0:768 of QKb), z 96..191 -> K panel (cols 768:1536).
// ---------------------------------------------------------------------------
__global__ __launch_bounds__(256) void head_tr(const u16* __restrict__ QKb,
                                               u16* __restrict__ QbT,
                                               u16* __restrict__ KbT) {
  __shared__ u16 T[64][72];
  const int t = threadIdx.x;
  const int z = blockIdx.z;
  const int half = (z >= 96) ? 1 : 0;
  const int bhh = z - 96 * half;
  const u16* ip = QKb + (size_t)(bhh / Hq) * Nq * QKP + (bhh % Hq) * 64 + half * Dq
                + (size_t)(blockIdx.y * 64) * QKP;
  u16* op = (half ? KbT : QbT) + (size_t)bhh * 64 * Nq + blockIdx.y * 64;
  const int r = t >> 3, c8 = (t & 7) * 8;
#pragma unroll
  for (int p = 0; p < 2; p++)
    *(uint4*)&T[r + p * 32][c8] = *(const uint4*)(ip + (size_t)(r + p * 32) * QKP + c8);
  __syncthreads();
#pragma unroll
  for (int p = 0; p < 2; p++) {
    int oc = r + p * 32;
    u16 tmp[8];
#pragma unroll
    for (int j = 0; j < 8; j++) tmp[j] = T[c8 + j][oc];
    *(uint4*)(op + (size_t)oc * Nq + c8) = *(uint4*)tmp;
  }
}

// ---------------------------------------------------------------------------
// bf16 MFMA GEMM: C[M,N] = A[M,K] * B[N,K]^T, bf16 out. 128x128 tile, BK=32,
// double-buffered single-barrier pipeline. XCD-swizzled. LDS 32 KB.
// ---------------------------------------------------------------------------
template<bool RELU>
__global__ __launch_bounds__(256) void gemm_bf16(
    const u16* __restrict__ A, const u16* __restrict__ B, u16* __restrict__ C,
    int M, int N, int K) {
  __shared__ u16 As[2][128 * 32];
  __shared__ u16 Bs[2][128 * 32];
  int bx, by;
  xcd_swizzle(gridDim.x, gridDim.y, bx, by);
  const int t = threadIdx.x, l = t & 63, w = t >> 6;
  const int lq = l & 15, quad = l >> 4;
  const int bm = by * 128, bn = bx * 128;
  const int wm = (w & 1) * 64, wn = (w >> 1) * 64;
  f32x4 acc[4][4];
#pragma unroll
  for (int i = 0; i < 4; i++)
#pragma unroll
    for (int j = 0; j < 4; j++) acc[i][j] = (f32x4){0.f, 0.f, 0.f, 0.f};

  auto stage = [&](int k0, int bufi) {
#pragma unroll
    for (int p = 0; p < 2; p++) {
      int idx = p * 256 + t;
      GLOAD16(A + (size_t)(bm + (idx >> 2)) * K + k0 + (idx & 3) * 8, &As[bufi][idx * 8]);
      GLOAD16(B + (size_t)(bn + (idx >> 2)) * K + k0 + (idx & 3) * 8, &Bs[bufi][idx * 8]);
    }
  };
  stage(0, 0);
  const int nIter = K >> 5;
  for (int it = 0; it < nIter; it++) {
    __syncthreads();
    if (it + 1 < nIter) stage((it + 1) * 32, (it + 1) & 1);
    const int bi = it & 1;
    s16x8 af[4], bf[4];
#pragma unroll
    for (int mt = 0; mt < 4; mt++)
      af[mt] = *(const s16x8*)&As[bi][(wm + mt * 16 + lq) * 32 + quad * 8];
#pragma unroll
    for (int nt = 0; nt < 4; nt++)
      bf[nt] = *(const s16x8*)&Bs[bi][(wn + nt * 16 + lq) * 32 + quad * 8];
#pragma unroll
    for (int mt = 0; mt < 4; mt++)
#pragma unroll
      for (int nt = 0; nt < 4; nt++)
        acc[mt][nt] = MFMA16(af[mt], bf[nt], acc[mt][nt], 0, 0, 0);
  }
#pragma unroll
  for (int mt = 0; mt < 4; mt++)
#pragma unroll
    for (int nt = 0; nt < 4; nt++) {
      int row = bm + wm + mt * 16 + quad * 4;
      int col = bn + wn + nt * 16 + lq;
#pragma unroll
      for (int r = 0; r < 4; r++) {
        float v = acc[mt][nt][r];
        if (RELU) v = fmaxf(v, 0.f);
        C[(size_t)(row + r) * N + col] = f2bf(v);
      }
    }
}

// ---------------------------------------------------------------------------
// Fused output GEMM (no atomics, proven BK=64 form): 128x64 tile,
//   out = AV12[8192][1536] @ WqkT^T + hid[8192][3072] @ WmT^T
// BK=64 (72 tiles), double-buffered single-barrier pipeline. LDS 48 KB.
// grid (12, 64) = 768 blocks, XCD-swizzled. Measured 85-88 us across 4 rounds.
// ---------------------------------------------------------------------------
__global__ __launch_bounds__(256) void gemm_out2(
    const u16* __restrict__ AV12, const u16* __restrict__ hid,
    const u16* __restrict__ WqkT, const u16* __restrict__ WmT,
    float* __restrict__ out) {
  __shared__ u16 As[2][128 * 64];   // 32 KB
  __shared__ u16 Bs[2][64 * 64];    // 16 KB
  int bx, by;
  xcd_swizzle(gridDim.x, gridDim.y, bx, by);
  const int t = threadIdx.x, l = t & 63, w = t >> 6;
  const int lq = l & 15, quad = l >> 4;
  const int bm = by * 128, bn = bx * 64;
  const int wm = w * 32;
  f32x4 acc[2][4];
#pragma unroll
  for (int i = 0; i < 2; i++)
#pragma unroll
    for (int j = 0; j < 4; j++) acc[i][j] = (f32x4){0.f, 0.f, 0.f, 0.f};

  // tiles 0..23 = AV12/WqkT (K=1536), 24..71 = hid/WmT (K=3072)
  auto stage = [&](int tl, int bufi) {
    const u16* A; const u16* B; int pitch, k0;
    if (tl < 24) { A = AV12; B = WqkT; pitch = QKP;  k0 = tl * 64; }
    else         { A = hid;  B = WmT;  pitch = HIDq; k0 = (tl - 24) * 64; }
#pragma unroll
    for (int p = 0; p < 4; p++) {
      int idx = p * 256 + t, ks = idx >> 9, rem = idx & 511;
      GLOAD16(A + (size_t)(bm + (rem >> 2)) * pitch + k0 + ks * 32 + (rem & 3) * 8,
              &As[bufi][idx * 8]);
    }
#pragma unroll
    for (int p = 0; p < 2; p++) {
      int idx = p * 256 + t, ks = idx >> 8, rem = idx & 255;
      GLOAD16(B + (size_t)(bn + (rem >> 2)) * pitch + k0 + ks * 32 + (rem & 3) * 8,
              &Bs[bufi][idx * 8]);
    }
  };
  stage(0, 0);
  for (int tl = 0; tl < 72; tl++) {
    __syncthreads();
    if (tl + 1 < 72) stage(tl + 1, (tl + 1) & 1);
    const int bi = tl & 1;
#pragma unroll
    for (int ks = 0; ks < 2; ks++) {
      s16x8 af[2], bf[4];
#pragma unroll
      for (int mt = 0; mt < 2; mt++)
        af[mt] = *(const s16x8*)&As[bi][ks * 4096 + (wm + mt * 16 + lq) * 32 + quad * 8];
#pragma unroll
      for (int nt = 0; nt < 4; nt++)
        bf[nt] = *(const s16x8*)&Bs[bi][ks * 2048 + (nt * 16 + lq) * 32 + quad * 8];
#pragma unroll
      for (int mt = 0; mt < 2; mt++)
#pragma unroll
        for (int nt = 0; nt < 4; nt++)
          acc[mt][nt] = MFMA16(af[mt], bf[nt], acc[mt][nt], 0, 0, 0);
    }
  }
#pragma unroll
  for (int mt = 0; mt < 2; mt++)
#pragma unroll
    for (int nt = 0; nt < 4; nt++) {
      int row = bm + wm + mt * 16 + quad * 4;
      int col = bn + nt * 16 + lq;
#pragma unroll
      for (int r = 0; r < 4; r++)
        out[(size_t)(row + r) * Dq + col] = acc[mt][nt][r];
    }
}

// ---------------------------------------------------------------------------
// Attention pass 1 (round-3 LDS-dieted version, measured best) + T5 setprio.
// Per (b,h,64-q). P = exp(beta*S), l = sum_k, AV1 = (P/l) @ K via MFMA.
// Qs overlaid on Ps; Ks single-buffered staged post-mid-barrier; Kts dbuf;
// red/li overlay Kts post-loop. 2 barriers/iter. 33 KB -> 4 blocks/CU.
// ---------------------------------------------------------------------------
__global__ __launch_bounds__(256) void attn_pass1(
    const u16* __restrict__ QKb, const u16* __restrict__ KbT,
    const float* __restrict__ betas, u16* __restrict__ AV12,
    float* __restrict__ lg) {
  __shared__ u16 Ps[64][72];         // 9216 B; first 4096 u16 double as Qs[2][64][32]
  __shared__ u16 Ks[2][64][32];      // 8 KB single-buffer [z-half][k-row][32]
  __shared__ u16 Kts[2][2][64][32];  // 16 KB dbuf [buf][k-half][z-row][32]

  const int t = threadIdx.x, l = t & 63, w = t >> 6;
  const int lq = l & 15, quad = l >> 4;
  const int c = blockIdx.x & 7, j = blockIdx.x >> 3;
  const int bh = c * 12 + j / 16, qt = j % 16;
  const int b = bh / Hq, h = bh % Hq;
  const int q0 = qt * 64;
  const float beta = betas[h];
  const u16* Qh = QKb + (size_t)(b * Nq) * QKP + h * 64;
  const u16* Kh = Qh + Dq;
  const u16* KTh = KbT + (size_t)bh * 64 * Nq;
  u16* QsF = &Ps[0][0];
  u16* KsF = &Ks[0][0][0];

  auto stageK = [&](int kt2) {
#pragma unroll
    for (int p = 0; p < 2; p++) {
      int idx = p * 256 + t;
      GLOAD16(Kh + (size_t)(kt2 * 64 + ((idx >> 2) & 63)) * QKP + (idx >> 8) * 32 + (idx & 3) * 8,
              KsF + idx * 8);
    }
  };
  auto stageKt = [&](int kt2, int bufi) {
#pragma unroll
    for (int p = 0; p < 2; p++) {
      int idx = p * 256 + t;
      GLOAD16(KTh + (size_t)((idx >> 2) & 63) * Nq + kt2 * 64 + (idx >> 8) * 32 + (idx & 3) * 8,
              &Kts[bufi][0][0][0] + idx * 8);
    }
  };

  // prologue: stage Q (into Ps region), K(0), Kt(0)
#pragma unroll
  for (int p = 0; p < 2; p++) {
    int idx = p * 256 + t;
    GLOAD16(Qh + (size_t)(q0 + ((idx >> 2) & 63)) * QKP + (idx >> 8) * 32 + (idx & 3) * 8,
            QsF + idx * 8);
  }
  stageK(0);
  stageKt(0, 0);
  __syncthreads();
  s16x8 bqf[2][4];
#pragma unroll
  for (int zs = 0; zs < 2; zs++)
#pragma unroll
    for (int nt = 0; nt < 4; nt++)
      bqf[zs][nt] = *(const s16x8*)&QsF[zs * 2048 + (nt * 16 + lq) * 32 + quad * 8];
  __syncthreads();                   // Qs consumed by ALL waves; Ps region free

  float lsum[4] = {0.f, 0.f, 0.f, 0.f};
  f32x4 ao[4];
#pragma unroll
  for (int nt = 0; nt < 4; nt++) ao[nt] = (f32x4){0.f, 0.f, 0.f, 0.f};

  for (int kt = 0; kt < 16; kt++) {
    if (kt) __syncthreads();         // top: Ks(kt), Kts[kt&1] landed; Ps consumed
    const int bi = kt & 1;
    // S^T tile: col q = nt*16+lq, row k = kt*64 + w*16 + quad*4 + r
    f32x4 sc[4];
#pragma unroll
    for (int nt = 0; nt < 4; nt++) sc[nt] = (f32x4){0.f, 0.f, 0.f, 0.f};
    __builtin_amdgcn_s_setprio(1);
#pragma unroll
    for (int zs = 0; zs < 2; zs++) {
      s16x8 a = *(const s16x8*)&Ks[zs][w * 16 + lq][quad * 8];
#pragma unroll
      for (int nt = 0; nt < 4; nt++)
        sc[nt] = MFMA16(a, bqf[zs][nt], sc[nt], 0, 0, 0);
    }
    __builtin_amdgcn_s_setprio(0);
#pragma unroll
    for (int nt = 0; nt < 4; nt++) {
      float e0 = __expf(sc[nt][0] * beta), e1 = __expf(sc[nt][1] * beta);
      float e2 = __expf(sc[nt][2] * beta), e3 = __expf(sc[nt][3] * beta);
      lsum[nt] += (e0 + e1) + (e2 + e3);
      uint2 pk; pk.x = pk2bf(e0, e1); pk.y = pk2bf(e2, e3);
      *(uint2*)&Ps[nt * 16 + lq][w * 16 + quad * 4] = pk;
    }
    __syncthreads();                 // mid: Ps visible; all Ks reads done
    if (kt + 1 < 16) {               // stage next tiles; drain at next top sync
      stageK(kt + 1);
      stageKt(kt + 1, (kt + 1) & 1);
    }
    // O[q][z] += P[q][k] * K[k][z]; B-frag reads Kt rows (z-major)
    __builtin_amdgcn_s_setprio(1);
#pragma unroll
    for (int ks = 0; ks < 2; ks++) {
      s16x8 a = *(const s16x8*)&Ps[w * 16 + lq][ks * 32 + quad * 8];
#pragma unroll
      for (int nt = 0; nt < 4; nt++) {
        s16x8 bk = *(const s16x8*)&Kts[bi][ks][nt * 16 + lq][quad * 8];
        ao[nt] = MFMA16(a, bk, ao[nt], 0, 0, 0);
      }
    }
    __builtin_amdgcn_s_setprio(0);
  }
  __syncthreads();                   // all PV reads done -> Kts overlay safe
  float* redp = (float*)&Kts[0][0][0][0];   // 256 f32
  float* lip  = redp + 256;                 // 64 f32
#pragma unroll
  for (int nt = 0; nt < 4; nt++) {
    float v = lsum[nt];
    v += __shfl_xor(v, 16, 64);
    v += __shfl_xor(v, 32, 64);
    if (l < 16) redp[w * 64 + nt * 16 + lq] = v;
  }
  __syncthreads();
  if (t < 64) {
    float s = redp[t] + redp[64 + t] + redp[128 + t] + redp[192 + t];
    lg[(size_t)bh * Nq + q0 + t] = s;
    lip[t] = 1.0f / s;
  }
  __syncthreads();
  u16* Oh = AV12 + (size_t)(b * Nq + q0) * QKP + h * 64;
  float lr[4];
#pragma unroll
  for (int r = 0; r < 4; r++) lr[r] = lip[w * 16 + quad * 4 + r];
#pragma unroll
  for (int nt = 0; nt < 4; nt++)
#pragma unroll
    for (int r = 0; r < 4; r++)
      Oh[(size_t)(w * 16 + quad * 4 + r) * QKP + nt * 16 + lq] = f2bf(ao[nt][r] * lr[r]);
}

// ---------------------------------------------------------------------------
// Attention pass 2 (round-3 version) + T5 setprio. Per (b,h,64-k).
// Recompute P from l, AV2[k,z] = sum_q P[q,k]/l[q] * Q[q,z]. Ks overlaid on
// Pts, Qs single-buffered (staged post-mid), Qts dbuf, li_s dbuf. ~34 KB.
// ---------------------------------------------------------------------------
__global__ __launch_bounds__(256) void attn_pass2(
    const u16* __restrict__ QKb, const u16* __restrict__ QbT,
    const float* __restrict__ betas, u16* __restrict__ AV12,
    const float* __restrict__ lg) {
  __shared__ u16 Pts[64][72];        // 9216 B; first 4096 u16 double as Ks[2][64][32]
  __shared__ u16 Qs[2][64][32];      // 8 KB single-buffer [z-half][q-row][32]
  __shared__ u16 Qts[2][2][64][32];  // 16 KB dbuf [buf][q-half][z-row][32]
  __shared__ float li_s[2][64];

  const int t = threadIdx.x, l = t & 63, w = t >> 6;
  const int lq = l & 15, quad = l >> 4;
  const int c = blockIdx.x & 7, j = blockIdx.x >> 3;
  const int bh = c * 12 + j / 16, kt = j % 16;
  const int b = bh / Hq, h = bh % Hq;
  const int k0 = kt * 64;
  const float beta = betas[h];
  const u16* Qh = QKb + (size_t)(b * Nq) * QKP + h * 64;
  const u16* Kh = Qh + Dq;
  const u16* QTh = QbT + (size_t)bh * 64 * Nq;
  u16* KsF = &Pts[0][0];
  u16* QsF = &Qs[0][0][0];

  auto stageQ = [&](int qt2) {
#pragma unroll
    for (int p = 0; p < 2; p++) {
      int idx = p * 256 + t;
      GLOAD16(Qh + (size_t)(qt2 * 64 + ((idx >> 2) & 63)) * QKP + (idx >> 8) * 32 + (idx & 3) * 8,
              QsF + idx * 8);
    }
  };
  auto stageQt = [&](int qt2, int bufi) {
#pragma unroll
    for (int p = 0; p < 2; p++) {
      int idx = p * 256 + t;
      GLOAD16(QTh + (size_t)((idx >> 2) & 63) * Nq + qt2 * 64 + (idx >> 8) * 32 + (idx & 3) * 8,
              &Qts[bufi][0][0][0] + idx * 8);
    }
  };

  // prologue: stage K (into Pts region), Q(0), Qt(0), li(0)
#pragma unroll
  for (int p = 0; p < 2; p++) {
    int idx = p * 256 + t;
    GLOAD16(Kh + (size_t)(k0 + ((idx >> 2) & 63)) * QKP + (idx >> 8) * 32 + (idx & 3) * 8,
            KsF + idx * 8);
  }
  stageQ(0);
  stageQt(0, 0);
  if (t < 64) li_s[0][t] = 1.0f / lg[(size_t)bh * Nq + t];
  __syncthreads();
  s16x8 bkf[2][4];
#pragma unroll
  for (int zs = 0; zs < 2; zs++)
#pragma unroll
    for (int nt = 0; nt < 4; nt++)
      bkf[zs][nt] = *(const s16x8*)&KsF[zs * 2048 + (nt * 16 + lq) * 32 + quad * 8];
  __syncthreads();                   // Ks consumed by ALL waves; Pts region free

  f32x4 ao[4];
#pragma unroll
  for (int nt = 0; nt < 4; nt++) ao[nt] = (f32x4){0.f, 0.f, 0.f, 0.f};

  for (int qt = 0; qt < 16; qt++) {
    if (qt) __syncthreads();         // top: Qs(qt), Qts[qt&1], li_s[qt&1] landed
    const int bi = qt & 1;
    // S tile: col k = nt*16+lq, row q = qt*64 + w*16 + quad*4 + r
    f32x4 sc[4];
#pragma unroll
    for (int nt = 0; nt < 4; nt++) sc[nt] = (f32x4){0.f, 0.f, 0.f, 0.f};
    __builtin_amdgcn_s_setprio(1);
#pragma unroll
    for (int zs = 0; zs < 2; zs++) {
      s16x8 a = *(const s16x8*)&Qs[zs][w * 16 + lq][quad * 8];
#pragma unroll
      for (int nt = 0; nt < 4; nt++)
        sc[nt] = MFMA16(a, bkf[zs][nt], sc[nt], 0, 0, 0);
    }
    __builtin_amdgcn_s_setprio(0);
    float lr[4];
#pragma unroll
    for (int r = 0; r < 4; r++) lr[r] = li_s[bi][w * 16 + quad * 4 + r];
#pragma unroll
    for (int nt = 0; nt < 4; nt++) {
      float e0 = __expf(sc[nt][0] * beta) * lr[0];
      float e1 = __expf(sc[nt][1] * beta) * lr[1];
      float e2 = __expf(sc[nt][2] * beta) * lr[2];
      float e3 = __expf(sc[nt][3] * beta) * lr[3];
      uint2 pk; pk.x = pk2bf(e0, e1); pk.y = pk2bf(e2, e3);
      *(uint2*)&Pts[nt * 16 + lq][w * 16 + quad * 4] = pk;
    }
    __syncthreads();                 // mid: Pts visible; all Qs reads done
    if (qt + 1 < 16) {               // stage next; drain at next top sync
      stageQ(qt + 1);
      stageQt(qt + 1, (qt + 1) & 1);
      if (t < 64) li_s[(qt + 1) & 1][t] = 1.0f / lg[(size_t)bh * Nq + (qt + 1) * 64 + t];
    }
    // AV2[k][z] += P^T[k][q] * Q[q][z]; B-frag reads Qt rows (z-major)
    __builtin_amdgcn_s_setprio(1);
#pragma unroll
    for (int qs = 0; qs < 2; qs++) {
      s16x8 a = *(const s16x8*)&Pts[w * 16 + lq][qs * 32 + quad * 8];
#pragma unroll
      for (int nt = 0; nt < 4; nt++) {
        s16x8 bq = *(const s16x8*)&Qts[bi][qs][nt * 16 + lq][quad * 8];
        ao[nt] = MFMA16(a, bq, ao[nt], 0, 0, 0);
      }
    }
    __builtin_amdgcn_s_setprio(0);
  }
  u16* Oh = AV12 + (size_t)(b * Nq + k0) * QKP + Dq + h * 64;
#pragma unroll
  for (int nt = 0; nt < 4; nt++)
#pragma unroll
    for (int r = 0; r < 4; r++)
      Oh[(size_t)(w * 16 + quad * 4 + r) * QKP + nt * 16 + lq] = f2bf(ao[nt][r]);
}

// ---------------------------------------------------------------------------
extern "C" void kernel_launch(void* const* d_in, const int* in_sizes, int n_in,
                              void* d_out, int out_size, void* d_ws, size_t ws_size,
                              hipStream_t stream) {
  const float* x     = (const float*)d_in[0];
  const float* Wq    = (const float*)d_in[1];
  const float* Wk    = (const float*)d_in[2];
  const float* betas = (const float*)d_in[3];
  const float* Wm    = (const float*)d_in[4];
  float* out = (float*)d_out;

  // workspace layout (u16 units); ~93.4 MiB
  u16* xb   = (u16*)d_ws;                      // 6,291,456
  u16* Wqkb = xb + (size_t)BN * Dq;            // 1,179,648  [1536][768]
  u16* Wmb  = Wqkb + (size_t)QKP * Dq;         // 2,359,296  [3072][768]
  u16* WqkT = Wmb + (size_t)HIDq * Dq;         // 1,179,648  [768][1536]
  u16* QKb  = WqkT + (size_t)Dq * QKP;         // 12,582,912 [8192][1536]
  u16* QbT  = QKb + (size_t)BN * QKP;          // 6,291,456  [96][64][1024]
  u16* KbT  = QbT + (size_t)Bq * Hq * Zq * Nq; // 6,291,456
  u16* AV12 = KbT + (size_t)Bq * Hq * Zq * Nq; // 12,582,912 [8192][1536]
  float* lg = (float*)(AV12 + (size_t)BN * QKP);
  u16* hidb = QKb;   // overlays QKb/QbT/KbT (dead after attention)
  u16* WmT  = xb;    // overlays xb (dead after MLP1), [768][3072]

  dim3 blk(256);
  cvt2<<<8448, blk, 0, stream>>>(x, xb, Wm, Wmb);
  cvt_tr2<<<dim3(12, 12, 2), blk, 0, stream>>>(Wq, Wk, Wqkb, WqkT);

  // QK = x @ [Wq;Wk]^T  -> bf16 [8192][1536]
  gemm_bf16<false><<<dim3(QKP / 128, BN / 128), blk, 0, stream>>>(
      xb, Wqkb, QKb, BN, QKP, Dq);

  // per-head transposes of Q and K (single dispatch)
  head_tr<<<dim3(1, 16, 192), blk, 0, stream>>>(QKb, QbT, KbT);

  // attention (round-3 64-tile version, 1536 blocks each)
  attn_pass1<<<Bq * Hq * 16, blk, 0, stream>>>(QKb, KbT, betas, AV12, lg);
  attn_pass2<<<Bq * Hq * 16, blk, 0, stream>>>(QKb, QbT, betas, AV12, lg);

  // MLP up-proj: hid = relu(x @ Wm^T) bf16 (overlays QKb/QbT/KbT)
  gemm_bf16<true><<<dim3(HIDq / 128, BN / 128), blk, 0, stream>>>(
      xb, Wmb, hidb, BN, HIDq, Dq);

  // Wm transpose into xb region (xb dead after MLP1)
  transpose_bf16<<<dim3(12, 48, 1), blk, 0, stream>>>(Wmb, WmT, Dq, HIDq, 1, 0, 0, 0, 0);

  // out = AV12 @ WqkT^T + hid @ WmT^T, single dispatch, no atomics
  gemm_out2<<<dim3(Dq / 64, BN / 128), blk, 0, stream>>>(AV12, hidb, WqkT, WmT, out);
}

// Round 8
// 347.391 us; speedup vs baseline: 1.0914x; 1.0172x over previous
//
#include <hip/hip_runtime.h>
#include <hip/hip_bf16.h>

#define Bq 8
#define Nq 1024
#define Dq 768
#define Hq 12
#define Zq 64
#define HIDq 3072
#define BN (Bq*Nq)            // 8192
#define QKP 1536              // pitch of fused QK / AV12 buffers

typedef unsigned short u16;
typedef short s16x8 __attribute__((ext_vector_type(8)));
typedef float f32x4 __attribute__((ext_vector_type(4)));
typedef unsigned short u16x4 __attribute__((ext_vector_type(4)));

#define MFMA16 __builtin_amdgcn_mfma_f32_16x16x32_bf16
#define GLOAD16(g, l) __builtin_amdgcn_global_load_lds( \
    (const __attribute__((address_space(1))) void*)(const void*)(g), \
    (__attribute__((address_space(3))) void*)(l), 16, 0, 0)

__device__ __forceinline__ u16 f2bf(float f) {
  unsigned u = __float_as_uint(f);
  return (u16)((u + 0x7FFFu + ((u >> 16) & 1u)) >> 16);
}

// paired f32->bf16 (v_cvt_pk_bf16_f32; RNE, matches f2bf)
__device__ __forceinline__ unsigned pk2bf(float a, float b) {
  union { __hip_bfloat162 h; unsigned u; } cv;
  cv.h.x = __float2bfloat16(a);
  cv.h.y = __float2bfloat16(b);
  return cv.u;
}

// XCD-aware swizzle: all gx tiles of a row-panel (and gy/8 consecutive panels)
// land on one XCD (dispatch round-robins linear id % 8). Requires gy % 8 == 0.
__device__ __forceinline__ void xcd_swizzle(int gx, int gy, int& bx, int& by) {
  int l = blockIdx.y * gx + blockIdx.x;
  int c = l & 7, j = l >> 3;
  by = c * (gy >> 3) + j / gx;
  bx = j % gx;
}

// ---------------------------------------------------------------------------
// f32 -> bf16 convert, TWO tensors in one dispatch (x then Wm)
// blocks 0..6143 -> x (BN*Dq), 6144..8447 -> Wm (HIDq*Dq)
// ---------------------------------------------------------------------------
__global__ __launch_bounds__(256) void cvt2(const float* __restrict__ x, u16* __restrict__ xb,
                                            const float* __restrict__ Wm, u16* __restrict__ Wmb) {
  int bid = blockIdx.x;
  const float* in; u16* out; int i;
  if (bid < 6144) { in = x;  out = xb;  i = bid * 1024 + threadIdx.x * 4; }
  else            { in = Wm; out = Wmb; i = (bid - 6144) * 1024 + threadIdx.x * 4; }
  float4 v = *(const float4*)&in[i];
  u16x4 o; o[0] = f2bf(v.x); o[1] = f2bf(v.y); o[2] = f2bf(v.z); o[3] = f2bf(v.w);
  *(u16x4*)&out[i] = o;
}

// ---------------------------------------------------------------------------
// Wq/Wk f32 [768][768] -> bf16 [row-major into Wqkb slab] AND transposed into
// WqkT [768][1536]. grid (12, 12, 2): z=0 -> Wq, z=1 -> Wk.
// ---------------------------------------------------------------------------
__global__ __launch_bounds__(256) void cvt_tr2(const float* __restrict__ Wq,
                                               const float* __restrict__ Wk,
                                               u16* __restrict__ Wqkb,
                                               u16* __restrict__ WqkT) {
  __shared__ u16 T[64][72];
  const int t = threadIdx.x;
  const int z = blockIdx.z;
  const float* in = z ? Wk : Wq;
  u16* out = Wqkb + (size_t)z * Dq * Dq;
  u16* outT = WqkT + z * Dq;
  const int r0 = blockIdx.y * 64, c0 = blockIdx.x * 64;
  const int r = t >> 3, c8 = (t & 7) * 8;
#pragma unroll
  for (int p = 0; p < 2; p++) {
    const float* ip = &in[(size_t)(r0 + r + p * 32) * Dq + c0 + c8];
    float4 v0 = *(const float4*)ip, v1 = *(const float4*)(ip + 4);
    u16 tmp[8] = {f2bf(v0.x), f2bf(v0.y), f2bf(v0.z), f2bf(v0.w),
                  f2bf(v1.x), f2bf(v1.y), f2bf(v1.z), f2bf(v1.w)};
    *(uint4*)&out[(size_t)(r0 + r + p * 32) * Dq + c0 + c8] = *(uint4*)tmp;
    *(uint4*)&T[r + p * 32][c8] = *(uint4*)tmp;
  }
  __syncthreads();
#pragma unroll
  for (int p = 0; p < 2; p++) {
    int oc = r + p * 32;
    u16 tmp[8];
#pragma unroll
    for (int j = 0; j < 8; j++) tmp[j] = T[c8 + j][oc];
    *(uint4*)&outT[(size_t)(c0 + oc) * QKP + r0 + c8] = *(uint4*)tmp;
  }
}

// ---------------------------------------------------------------------------
// Batched 64x64-tiled bf16 transpose (used for WmT only).
// ---------------------------------------------------------------------------
__global__ __launch_bounds__(256) void transpose_bf16(
    const u16* __restrict__ in, u16* __restrict__ out,
    int in_pitch, int out_pitch, int inner_n,
    long in_bs_o, long in_bs_i, long out_bs_o, long out_bs_i) {
  __shared__ u16 T[64][72];
  const int t = threadIdx.x;
  const int bz = blockIdx.z;
  const long iboff = (long)(bz / inner_n) * in_bs_o + (long)(bz % inner_n) * in_bs_i;
  const long oboff = (long)(bz / inner_n) * out_bs_o + (long)(bz % inner_n) * out_bs_i;
  const u16* ip = in + iboff + (long)(blockIdx.y * 64) * in_pitch + blockIdx.x * 64;
  u16* op = out + oboff + (long)(blockIdx.x * 64) * out_pitch + blockIdx.y * 64;
  const int r = t >> 3, c8 = (t & 7) * 8;
#pragma unroll
  for (int p = 0; p < 2; p++)
    *(uint4*)&T[r + p * 32][c8] = *(const uint4*)(ip + (size_t)(r + p * 32) * in_pitch + c8);
  __syncthreads();
#pragma unroll
  for (int p = 0; p < 2; p++) {
    int oc = r + p * 32;
    u16 tmp[8];
#pragma unroll
    for (int j = 0; j < 8; j++) tmp[j] = T[c8 + j][oc];
    *(uint4*)(op + (size_t)oc * out_pitch + c8) = *(uint4*)tmp;
  }
}

// ---------------------------------------------------------------------------
// bf16 MFMA GEMM: C[M,N] = A[M,K] * B[N,K]^T, bf16 out. 128x128 tile, BK=32,
// double-buffered single-barrier pipeline. XCD-swizzled. LDS 32 KB static.
// TRW (QK instantiation): additionally writes per-head transposed copies of C
// into QbT/KbT via a dynamic-LDS [128][68] transpose tile (17408 B dynamic ->
// 49.4 KB total -> 3 blocks/CU; grid 768 = 3/CU, fully resident). Each 64-col
// half of the 128-col tile is exactly one head panel (768 % 128 == 0).
// Bit-exact vs the old head_tr kernel (same f2bf-rounded values).
// ---------------------------------------------------------------------------
template<bool RELU, bool TRW>
__global__ __launch_bounds__(256) void gemm_bf16(
    const u16* __restrict__ A, const u16* __restrict__ B, u16* __restrict__ C,
    u16* __restrict__ QbT, u16* __restrict__ KbT,
    int M, int N, int K) {
  __shared__ u16 As[2][128 * 32];
  __shared__ u16 Bs[2][128 * 32];
  extern __shared__ u16 Ts[];        // TRW only: [128][68]
  int bx, by;
  xcd_swizzle(gridDim.x, gridDim.y, bx, by);
  const int t = threadIdx.x, l = t & 63, w = t >> 6;
  const int lq = l & 15, quad = l >> 4;
  const int bm = by * 128, bn = bx * 128;
  const int wm = (w & 1) * 64, wn = (w >> 1) * 64;
  f32x4 acc[4][4];
#pragma unroll
  for (int i = 0; i < 4; i++)
#pragma unroll
    for (int j = 0; j < 4; j++) acc[i][j] = (f32x4){0.f, 0.f, 0.f, 0.f};

  auto stage = [&](int k0, int bufi) {
#pragma unroll
    for (int p = 0; p < 2; p++) {
      int idx = p * 256 + t;
      GLOAD16(A + (size_t)(bm + (idx >> 2)) * K + k0 + (idx & 3) * 8, &As[bufi][idx * 8]);
      GLOAD16(B + (size_t)(bn + (idx >> 2)) * K + k0 + (idx & 3) * 8, &Bs[bufi][idx * 8]);
    }
  };
  stage(0, 0);
  const int nIter = K >> 5;
  for (int it = 0; it < nIter; it++) {
    __syncthreads();
    if (it + 1 < nIter) stage((it + 1) * 32, (it + 1) & 1);
    const int bi = it & 1;
    s16x8 af[4], bf[4];
#pragma unroll
    for (int mt = 0; mt < 4; mt++)
      af[mt] = *(const s16x8*)&As[bi][(wm + mt * 16 + lq) * 32 + quad * 8];
#pragma unroll
    for (int nt = 0; nt < 4; nt++)
      bf[nt] = *(const s16x8*)&Bs[bi][(wn + nt * 16 + lq) * 32 + quad * 8];
#pragma unroll
    for (int mt = 0; mt < 4; mt++)
#pragma unroll
      for (int nt = 0; nt < 4; nt++)
        acc[mt][nt] = MFMA16(af[mt], bf[nt], acc[mt][nt], 0, 0, 0);
  }
#pragma unroll
  for (int mt = 0; mt < 4; mt++)
#pragma unroll
    for (int nt = 0; nt < 4; nt++) {
      int row = bm + wm + mt * 16 + quad * 4;
      int col = bn + wn + nt * 16 + lq;
#pragma unroll
      for (int r = 0; r < 4; r++) {
        float v = acc[mt][nt][r];
        if (RELU) v = fmaxf(v, 0.f);
        C[(size_t)(row + r) * N + col] = f2bf(v);
      }
    }
  if constexpr (TRW) {
    // per-head transposed write: half hf covers cols sb..sb+64 = one head
    const int b = bm >> 10, n0 = bm & 1023;
#pragma unroll
    for (int hf = 0; hf < 2; hf++) {
      __syncthreads();                       // Ts free (prev half's reads done)
      if ((w >> 1) == hf) {                  // 2 waves own this col-half
#pragma unroll
        for (int mt = 0; mt < 4; mt++)
#pragma unroll
          for (int nt = 0; nt < 4; nt++)
#pragma unroll
            for (int r = 0; r < 4; r++)
              Ts[(wm + mt * 16 + quad * 4 + r) * 68 + nt * 16 + lq] =
                  f2bf(acc[mt][nt][r]);
      }
      __syncthreads();                       // Ts populated
      const int sb = bn + hf * 64;
      const int half = sb >= Dq;
      const int h = (sb - half * Dq) >> 6;
      u16* dst = (half ? KbT : QbT) + (size_t)(b * Hq + h) * 64 * Nq;
#pragma unroll
      for (int p = 0; p < 4; p++) {
        int u = p * 256 + t, zc = u >> 4, un8 = (u & 15) * 8;
        u16 tmp[8];
#pragma unroll
        for (int j = 0; j < 8; j++) tmp[j] = Ts[(un8 + j) * 68 + zc];
        *(uint4*)&dst[(size_t)zc * Nq + n0 + un8] = *(uint4*)tmp;
      }
    }
  }
}

// ---------------------------------------------------------------------------
// Fused output GEMM (no atomics, proven BK=64 form): 128x64 tile,
//   out = AV12[8192][1536] @ WqkT^T + hid[8192][3072] @ WmT^T
// BK=64 (72 tiles), double-buffered single-barrier pipeline. LDS 48 KB.
// grid (12, 64) = 768 blocks, XCD-swizzled. Measured 84-88 us across rounds.
// ---------------------------------------------------------------------------
__global__ __launch_bounds__(256) void gemm_out2(
    const u16* __restrict__ AV12, const u16* __restrict__ hid,
    const u16* __restrict__ WqkT, const u16* __restrict__ WmT,
    float* __restrict__ out) {
  __shared__ u16 As[2][128 * 64];   // 32 KB
  __shared__ u16 Bs[2][64 * 64];    // 16 KB
  int bx, by;
  xcd_swizzle(gridDim.x, gridDim.y, bx, by);
  const int t = threadIdx.x, l = t & 63, w = t >> 6;
  const int lq = l & 15, quad = l >> 4;
  const int bm = by * 128, bn = bx * 64;
  const int wm = w * 32;
  f32x4 acc[2][4];
#pragma unroll
  for (int i = 0; i < 2; i++)
#pragma unroll
    for (int j = 0; j < 4; j++) acc[i][j] = (f32x4){0.f, 0.f, 0.f, 0.f};

  // tiles 0..23 = AV12/WqkT (K=1536), 24..71 = hid/WmT (K=3072)
  auto stage = [&](int tl, int bufi) {
    const u16* A; const u16* B; int pitch, k0;
    if (tl < 24) { A = AV12; B = WqkT; pitch = QKP;  k0 = tl * 64; }
    else         { A = hid;  B = WmT;  pitch = HIDq; k0 = (tl - 24) * 64; }
#pragma unroll
    for (int p = 0; p < 4; p++) {
      int idx = p * 256 + t, ks = idx >> 9, rem = idx & 511;
      GLOAD16(A + (size_t)(bm + (rem >> 2)) * pitch + k0 + ks * 32 + (rem & 3) * 8,
              &As[bufi][idx * 8]);
    }
#pragma unroll
    for (int p = 0; p < 2; p++) {
      int idx = p * 256 + t, ks = idx >> 8, rem = idx & 255;
      GLOAD16(B + (size_t)(bn + (rem >> 2)) * pitch + k0 + ks * 32 + (rem & 3) * 8,
              &Bs[bufi][idx * 8]);
    }
  };
  stage(0, 0);
  for (int tl = 0; tl < 72; tl++) {
    __syncthreads();
    if (tl + 1 < 72) stage(tl + 1, (tl + 1) & 1);
    const int bi = tl & 1;
#pragma unroll
    for (int ks = 0; ks < 2; ks++) {
      s16x8 af[2], bf[4];
#pragma unroll
      for (int mt = 0; mt < 2; mt++)
        af[mt] = *(const s16x8*)&As[bi][ks * 4096 + (wm + mt * 16 + lq) * 32 + quad * 8];
#pragma unroll
      for (int nt = 0; nt < 4; nt++)
        bf[nt] = *(const s16x8*)&Bs[bi][ks * 2048 + (nt * 16 + lq) * 32 + quad * 8];
#pragma unroll
      for (int mt = 0; mt < 2; mt++)
#pragma unroll
        for (int nt = 0; nt < 4; nt++)
          acc[mt][nt] = MFMA16(af[mt], bf[nt], acc[mt][nt], 0, 0, 0);
    }
  }
#pragma unroll
  for (int mt = 0; mt < 2; mt++)
#pragma unroll
    for (int nt = 0; nt < 4; nt++) {
      int row = bm + wm + mt * 16 + quad * 4;
      int col = bn + nt * 16 + lq;
#pragma unroll
      for (int r = 0; r < 4; r++)
        out[(size_t)(row + r) * Dq + col] = acc[mt][nt][r];
    }
}

// ---------------------------------------------------------------------------
// Attention pass 1 (round-3 LDS-dieted version, measured best) + T5 setprio.
// Per (b,h,64-q). P = exp(beta*S), l = sum_k, AV1 = (P/l) @ K via MFMA.
// Qs overlaid on Ps; Ks single-buffered staged post-mid-barrier; Kts dbuf;
// red/li overlay Kts post-loop. 2 barriers/iter. 33 KB -> 4 blocks/CU.
// ---------------------------------------------------------------------------
__global__ __launch_bounds__(256) void attn_pass1(
    const u16* __restrict__ QKb, const u16* __restrict__ KbT,
    const float* __restrict__ betas, u16* __restrict__ AV12,
    float* __restrict__ lg) {
  __shared__ u16 Ps[64][72];         // 9216 B; first 4096 u16 double as Qs[2][64][32]
  __shared__ u16 Ks[2][64][32];      // 8 KB single-buffer [z-half][k-row][32]
  __shared__ u16 Kts[2][2][64][32];  // 16 KB dbuf [buf][k-half][z-row][32]

  const int t = threadIdx.x, l = t & 63, w = t >> 6;
  const int lq = l & 15, quad = l >> 4;
  const int c = blockIdx.x & 7, j = blockIdx.x >> 3;
  const int bh = c * 12 + j / 16, qt = j % 16;
  const int b = bh / Hq, h = bh % Hq;
  const int q0 = qt * 64;
  const float beta = betas[h];
  const u16* Qh = QKb + (size_t)(b * Nq) * QKP + h * 64;
  const u16* Kh = Qh + Dq;
  const u16* KTh = KbT + (size_t)bh * 64 * Nq;
  u16* QsF = &Ps[0][0];
  u16* KsF = &Ks[0][0][0];

  auto stageK = [&](int kt2) {
#pragma unroll
    for (int p = 0; p < 2; p++) {
      int idx = p * 256 + t;
      GLOAD16(Kh + (size_t)(kt2 * 64 + ((idx >> 2) & 63)) * QKP + (idx >> 8) * 32 + (idx & 3) * 8,
              KsF + idx * 8);
    }
  };
  auto stageKt = [&](int kt2, int bufi) {
#pragma unroll
    for (int p = 0; p < 2; p++) {
      int idx = p * 256 + t;
      GLOAD16(KTh + (size_t)((idx >> 2) & 63) * Nq + kt2 * 64 + (idx >> 8) * 32 + (idx & 3) * 8,
              &Kts[bufi][0][0][0] + idx * 8);
    }
  };

  // prologue: stage Q (into Ps region), K(0), Kt(0)
#pragma unroll
  for (int p = 0; p < 2; p++) {
    int idx = p * 256 + t;
    GLOAD16(Qh + (size_t)(q0 + ((idx >> 2) & 63)) * QKP + (idx >> 8) * 32 + (idx & 3) * 8,
            QsF + idx * 8);
  }
  stageK(0);
  stageKt(0, 0);
  __syncthreads();
  s16x8 bqf[2][4];
#pragma unroll
  for (int zs = 0; zs < 2; zs++)
#pragma unroll
    for (int nt = 0; nt < 4; nt++)
      bqf[zs][nt] = *(const s16x8*)&QsF[zs * 2048 + (nt * 16 + lq) * 32 + quad * 8];
  __syncthreads();                   // Qs consumed by ALL waves; Ps region free

  float lsum[4] = {0.f, 0.f, 0.f, 0.f};
  f32x4 ao[4];
#pragma unroll
  for (int nt = 0; nt < 4; nt++) ao[nt] = (f32x4){0.f, 0.f, 0.f, 0.f};

  for (int kt = 0; kt < 16; kt++) {
    if (kt) __syncthreads();         // top: Ks(kt), Kts[kt&1] landed; Ps consumed
    const int bi = kt & 1;
    // S^T tile: col q = nt*16+lq, row k = kt*64 + w*16 + quad*4 + r
    f32x4 sc[4];
#pragma unroll
    for (int nt = 0; nt < 4; nt++) sc[nt] = (f32x4){0.f, 0.f, 0.f, 0.f};
    __builtin_amdgcn_s_setprio(1);
#pragma unroll
    for (int zs = 0; zs < 2; zs++) {
      s16x8 a = *(const s16x8*)&Ks[zs][w * 16 + lq][quad * 8];
#pragma unroll
      for (int nt = 0; nt < 4; nt++)
        sc[nt] = MFMA16(a, bqf[zs][nt], sc[nt], 0, 0, 0);
    }
    __builtin_amdgcn_s_setprio(0);
#pragma unroll
    for (int nt = 0; nt < 4; nt++) {
      float e0 = __expf(sc[nt][0] * beta), e1 = __expf(sc[nt][1] * beta);
      float e2 = __expf(sc[nt][2] * beta), e3 = __expf(sc[nt][3] * beta);
      lsum[nt] += (e0 + e1) + (e2 + e3);
      uint2 pk; pk.x = pk2bf(e0, e1); pk.y = pk2bf(e2, e3);
      *(uint2*)&Ps[nt * 16 + lq][w * 16 + quad * 4] = pk;
    }
    __syncthreads();                 // mid: Ps visible; all Ks reads done
    if (kt + 1 < 16) {               // stage next tiles; drain at next top sync
      stageK(kt + 1);
      stageKt(kt + 1, (kt + 1) & 1);
    }
    // O[q][z] += P[q][k] * K[k][z]; B-frag reads Kt rows (z-major)
    __builtin_amdgcn_s_setprio(1);
#pragma unroll
    for (int ks = 0; ks < 2; ks++) {
      s16x8 a = *(const s16x8*)&Ps[w * 16 + lq][ks * 32 + quad * 8];
#pragma unroll
      for (int nt = 0; nt < 4; nt++) {
        s16x8 bk = *(const s16x8*)&Kts[bi][ks][nt * 16 + lq][quad * 8];
        ao[nt] = MFMA16(a, bk, ao[nt], 0, 0, 0);
      }
    }
    __builtin_amdgcn_s_setprio(0);
  }
  __syncthreads();                   // all PV reads done -> Kts overlay safe
  float* redp = (float*)&Kts[0][0][0][0];   // 256 f32
  float* lip  = redp + 256;                 // 64 f32
#pragma unroll
  for (int nt = 0; nt < 4; nt++) {
    float v = lsum[nt];
    v += __shfl_xor(v, 16, 64);
    v += __shfl_xor(v, 32, 64);
    if (l < 16) redp[w * 64 + nt * 16 + lq] = v;
  }
  __syncthreads();
  if (t < 64) {
    float s = redp[t] + redp[64 + t] + redp[128 + t] + redp[192 + t];
    lg[(size_t)bh * Nq + q0 + t] = s;
    lip[t] = 1.0f / s;
  }
  __syncthreads();
  u16* Oh = AV12 + (size_t)(b * Nq + q0) * QKP + h * 64;
  float lr[4];
#pragma unroll
  for (int r = 0; r < 4; r++) lr[r] = lip[w * 16 + quad * 4 + r];
#pragma unroll
  for (int nt = 0; nt < 4; nt++)
#pragma unroll
    for (int r = 0; r < 4; r++)
      Oh[(size_t)(w * 16 + quad * 4 + r) * QKP + nt * 16 + lq] = f2bf(ao[nt][r] * lr[r]);
}

// ---------------------------------------------------------------------------
// Attention pass 2 (round-3 version) + T5 setprio. Per (b,h,64-k).
// Recompute P from l, AV2[k,z] = sum_q P[q,k]/l[q] * Q[q,z]. Ks overlaid on
// Pts, Qs single-buffered (staged post-mid), Qts dbuf, li_s dbuf. ~34 KB.
// ---------------------------------------------------------------------------
__global__ __launch_bounds__(256) void attn_pass2(
    const u16* __restrict__ QKb, const u16* __restrict__ QbT,
    const float* __restrict__ betas, u16* __restrict__ AV12,
    const float* __restrict__ lg) {
  __shared__ u16 Pts[64][72];        // 9216 B; first 4096 u16 double as Ks[2][64][32]
  __shared__ u16 Qs[2][64][32];      // 8 KB single-buffer [z-half][q-row][32]
  __shared__ u16 Qts[2][2][64][32];  // 16 KB dbuf [buf][q-half][z-row][32]
  __shared__ float li_s[2][64];

  const int t = threadIdx.x, l = t & 63, w = t >> 6;
  const int lq = l & 15, quad = l >> 4;
  const int c = blockIdx.x & 7, j = blockIdx.x >> 3;
  const int bh = c * 12 + j / 16, kt = j % 16;
  const int b = bh / Hq, h = bh % Hq;
  const int k0 = kt * 64;
  const float beta = betas[h];
  const u16* Qh = QKb + (size_t)(b * Nq) * QKP + h * 64;
  const u16* Kh = Qh + Dq;
  const u16* QTh = QbT + (size_t)bh * 64 * Nq;
  u16* KsF = &Pts[0][0];
  u16* QsF = &Qs[0][0][0];

  auto stageQ = [&](int qt2) {
#pragma unroll
    for (int p = 0; p < 2; p++) {
      int idx = p * 256 + t;
      GLOAD16(Qh + (size_t)(qt2 * 64 + ((idx >> 2) & 63)) * QKP + (idx >> 8) * 32 + (idx & 3) * 8,
              QsF + idx * 8);
    }
  };
  auto stageQt = [&](int qt2, int bufi) {
#pragma unroll
    for (int p = 0; p < 2; p++) {
      int idx = p * 256 + t;
      GLOAD16(QTh + (size_t)((idx >> 2) & 63) * Nq + qt2 * 64 + (idx >> 8) * 32 + (idx & 3) * 8,
              &Qts[bufi][0][0][0] + idx * 8);
    }
  };

  // prologue: stage K (into Pts region), Q(0), Qt(0), li(0)
#pragma unroll
  for (int p = 0; p < 2; p++) {
    int idx = p * 256 + t;
    GLOAD16(Kh + (size_t)(k0 + ((idx >> 2) & 63)) * QKP + (idx >> 8) * 32 + (idx & 3) * 8,
            KsF + idx * 8);
  }
  stageQ(0);
  stageQt(0, 0);
  if (t < 64) li_s[0][t] = 1.0f / lg[(size_t)bh * Nq + t];
  __syncthreads();
  s16x8 bkf[2][4];
#pragma unroll
  for (int zs = 0; zs < 2; zs++)
#pragma unroll
    for (int nt = 0; nt < 4; nt++)
      bkf[zs][nt] = *(const s16x8*)&KsF[zs * 2048 + (nt * 16 + lq) * 32 + quad * 8];
  __syncthreads();                   // Ks consumed by ALL waves; Pts region free

  f32x4 ao[4];
#pragma unroll
  for (int nt = 0; nt < 4; nt++) ao[nt] = (f32x4){0.f, 0.f, 0.f, 0.f};

  for (int qt = 0; qt < 16; qt++) {
    if (qt) __syncthreads();         // top: Qs(qt), Qts[qt&1], li_s[qt&1] landed
    const int bi = qt & 1;
    // S tile: col k = nt*16+lq, row q = qt*64 + w*16 + quad*4 + r
    f32x4 sc[4];
#pragma unroll
    for (int nt = 0; nt < 4; nt++) sc[nt] = (f32x4){0.f, 0.f, 0.f, 0.f};
    __builtin_amdgcn_s_setprio(1);
#pragma unroll
    for (int zs = 0; zs < 2; zs++) {
      s16x8 a = *(const s16x8*)&Qs[zs][w * 16 + lq][quad * 8];
#pragma unroll
      for (int nt = 0; nt < 4; nt++)
        sc[nt] = MFMA16(a, bkf[zs][nt], sc[nt], 0, 0, 0);
    }
    __builtin_amdgcn_s_setprio(0);
    float lr[4];
#pragma unroll
    for (int r = 0; r < 4; r++) lr[r] = li_s[bi][w * 16 + quad * 4 + r];
#pragma unroll
    for (int nt = 0; nt < 4; nt++) {
      float e0 = __expf(sc[nt][0] * beta) * lr[0];
      float e1 = __expf(sc[nt][1] * beta) * lr[1];
      float e2 = __expf(sc[nt][2] * beta) * lr[2];
      float e3 = __expf(sc[nt][3] * beta) * lr[3];
      uint2 pk; pk.x = pk2bf(e0, e1); pk.y = pk2bf(e2, e3);
      *(uint2*)&Pts[nt * 16 + lq][w * 16 + quad * 4] = pk;
    }
    __syncthreads();                 // mid: Pts visible; all Qs reads done
    if (qt + 1 < 16) {               // stage next; drain at next top sync
      stageQ(qt + 1);
      stageQt(qt + 1, (qt + 1) & 1);
      if (t < 64) li_s[(qt + 1) & 1][t] = 1.0f / lg[(size_t)bh * Nq + (qt + 1) * 64 + t];
    }
    // AV2[k][z] += P^T[k][q] * Q[q][z]; B-frag reads Qt rows (z-major)
    __builtin_amdgcn_s_setprio(1);
#pragma unroll
    for (int qs = 0; qs < 2; qs++) {
      s16x8 a = *(const s16x8*)&Pts[w * 16 + lq][qs * 32 + quad * 8];
#pragma unroll
      for (int nt = 0; nt < 4; nt++) {
        s16x8 bq = *(const s16x8*)&Qts[bi][qs][nt * 16 + lq][quad * 8];
        ao[nt] = MFMA16(a, bq, ao[nt], 0, 0, 0);
      }
    }
    __builtin_amdgcn_s_setprio(0);
  }
  u16* Oh = AV12 + (size_t)(b * Nq + k0) * QKP + Dq + h * 64;
#pragma unroll
  for (int nt = 0; nt < 4; nt++)
#pragma unroll
    for (int r = 0; r < 4; r++)
      Oh[(size_t)(w * 16 + quad * 4 + r) * QKP + nt * 16 + lq] = f2bf(ao[nt][r]);
}

// ---------------------------------------------------------------------------
extern "C" void kernel_launch(void* const* d_in, const int* in_sizes, int n_in,
                              void* d_out, int out_size, void* d_ws, size_t ws_size,
                              hipStream_t stream) {
  const float* x     = (const float*)d_in[0];
  const float* Wq    = (const float*)d_in[1];
  const float* Wk    = (const float*)d_in[2];
  const float* betas = (const float*)d_in[3];
  const float* Wm    = (const float*)d_in[4];
  float* out = (float*)d_out;

  // workspace layout (u16 units); ~93.4 MiB
  u16* xb   = (u16*)d_ws;                      // 6,291,456
  u16* Wqkb = xb + (size_t)BN * Dq;            // 1,179,648  [1536][768]
  u16* Wmb  = Wqkb + (size_t)QKP * Dq;         // 2,359,296  [3072][768]
  u16* WqkT = Wmb + (size_t)HIDq * Dq;         // 1,179,648  [768][1536]
  u16* QKb  = WqkT + (size_t)Dq * QKP;         // 12,582,912 [8192][1536]
  u16* QbT  = QKb + (size_t)BN * QKP;          // 6,291,456  [96][64][1024]
  u16* KbT  = QbT + (size_t)Bq * Hq * Zq * Nq; // 6,291,456
  u16* AV12 = KbT + (size_t)Bq * Hq * Zq * Nq; // 12,582,912 [8192][1536]
  float* lg = (float*)(AV12 + (size_t)BN * QKP);
  u16* hidb = QKb;   // overlays QKb/QbT/KbT (dead after attention)
  u16* WmT  = xb;    // overlays xb (dead after MLP1), [768][3072]

  dim3 blk(256);
  cvt2<<<8448, blk, 0, stream>>>(x, xb, Wm, Wmb);
  cvt_tr2<<<dim3(12, 12, 2), blk, 0, stream>>>(Wq, Wk, Wqkb, WqkT);

  // QK = x @ [Wq;Wk]^T -> bf16 [8192][1536], PLUS fused per-head transposed
  // writes into QbT/KbT (replaces the old head_tr dispatch).
  gemm_bf16<false, true><<<dim3(QKP / 128, BN / 128), blk, 128 * 68 * 2, stream>>>(
      xb, Wqkb, QKb, QbT, KbT, BN, QKP, Dq);

  // attention (round-3 64-tile version + setprio, 1536 blocks each)
  attn_pass1<<<Bq * Hq * 16, blk, 0, stream>>>(QKb, KbT, betas, AV12, lg);
  attn_pass2<<<Bq * Hq * 16, blk, 0, stream>>>(QKb, QbT, betas, AV12, lg);

  // MLP up-proj: hid = relu(x @ Wm^T) bf16 (overlays QKb/QbT/KbT)
  gemm_bf16<true, false><<<dim3(HIDq / 128, BN / 128), blk, 0, stream>>>(
      xb, Wmb, hidb, nullptr, nullptr, BN, HIDq, Dq);

  // Wm transpose into xb region (xb dead after MLP1)
  transpose_bf16<<<dim3(12, 48, 1), blk, 0, stream>>>(Wmb, WmT, Dq, HIDq, 1, 0, 0, 0, 0);

  // out = AV12 @ WqkT^T + hid @ WmT^T, single dispatch, no atomics
  gemm_out2<<<dim3(Dq / 64, BN / 128), blk, 0, stream>>>(AV12, hidb, WqkT, WmT, out);
}